// Round 1
// baseline (8976.876 us; speedup 1.0000x reference)
//
#include <hip/hip_runtime.h>
#include <math.h>

// ---------------- constants ----------------
// B=4, T=32, IMG=84, P=14, D=768, H=12, L=3, GP=6, NP=36, N=37, FF=3072, HD=64
// tokens total = 4*32*37 = 4736 (both spatial flat and temporal flat)

#define NTOK 4736
#define DM   768
#define NHEAD 12

// ---------------- im2col: (128,3,84,84) -> (4608, 588) ----------------
__global__ __launch_bounds__(256) void im2col_k(const float* __restrict__ x,
                                                float* __restrict__ col) {
  int i = blockIdx.x * 256 + threadIdx.x;       // < 4608*588 = 2709504
  int r = i / 588, k = i % 588;
  int bt = r / 36, p = r % 36;
  int gy = p / 6, gx = p % 6;
  int c = k / 196, rem = k % 196;
  int ky = rem / 14, kx = rem % 14;
  col[i] = x[(((size_t)bt * 3 + c) * 84 + gy * 14 + ky) * 84 + gx * 14 + kx];
}

// ---------------- token assembly: cls + patches + pos ----------------
__global__ __launch_bounds__(256) void assemble_k(const float* __restrict__ conv_out,
                                                  const float* __restrict__ cls,
                                                  const float* __restrict__ pos,
                                                  float* __restrict__ X) {
  int i = blockIdx.x * 256 + threadIdx.x;       // < 4736*768
  int t = i / DM, d = i % DM;
  int bt = t / 37, n = t % 37;
  float v = (n == 0) ? cls[d] : conv_out[((size_t)bt * 36 + (n - 1)) * DM + d];
  X[i] = v + pos[n * DM + d];
}

// ---------------- temporal pos add ----------------
__global__ __launch_bounds__(256) void tpos_k(float* __restrict__ X,
                                              const float* __restrict__ tpos) {
  int i = blockIdx.x * 256 + threadIdx.x;       // < 4736*768
  int row = i / DM, d = i % DM;
  int tt = (row % 1184) / 37;                   // frame index 0..31
  X[i] += tpos[tt * DM + d];
}

// ---------------- LayerNorm over 768, one block per row ----------------
__global__ __launch_bounds__(256) void ln_k(const float* __restrict__ in,
                                            const float* __restrict__ g,
                                            const float* __restrict__ b,
                                            float* __restrict__ out) {
  int r = blockIdx.x;
  int tid = threadIdx.x;
  const float* xr = in + (size_t)r * DM;
  float v0 = xr[tid], v1 = xr[tid + 256], v2 = xr[tid + 512];
  float s  = v0 + v1 + v2;
  float sq = v0 * v0 + v1 * v1 + v2 * v2;
#pragma unroll
  for (int off = 32; off; off >>= 1) {
    s  += __shfl_down(s, off);
    sq += __shfl_down(sq, off);
  }
  __shared__ float ss[4], sg[4];
  if ((tid & 63) == 0) { ss[tid >> 6] = s; sg[tid >> 6] = sq; }
  __syncthreads();
  float S = ss[0] + ss[1] + ss[2] + ss[3];
  float Q = sg[0] + sg[1] + sg[2] + sg[3];
  float mean = S * (1.f / 768.f);
  float var  = Q * (1.f / 768.f) - mean * mean;
  float rs = rsqrtf(var + 1e-5f);
  float* o = out + (size_t)r * DM;
  o[tid]       = (v0 - mean) * rs * g[tid]       + b[tid];
  o[tid + 256] = (v1 - mean) * rs * g[tid + 256] + b[tid + 256];
  o[tid + 512] = (v2 - mean) * rs * g[tid + 512] + b[tid + 512];
}

// ---------------- generic fp32 GEMM: C = A(MxK) * B(KxN) [+bias][gelu][+r1][+r2]
// BT=true: B given as NxK row-major (conv weight). 64x64 tile, 4x4/thread.
template <bool BT, bool GELU>
__global__ __launch_bounds__(256) void gemm_k(const float* __restrict__ A,
                                              const float* __restrict__ B,
                                              const float* __restrict__ bias,
                                              const float* __restrict__ r1,
                                              const float* __restrict__ r2,
                                              float* __restrict__ C,
                                              int M, int N, int K) {
  __shared__ float As[16][68];   // [k][m], pad to 68 floats (272B, 16B-aligned rows)
  __shared__ float Bs[16][68];   // [k][n]
  const int bm = blockIdx.x * 64, bn = blockIdx.y * 64;
  const int tid = threadIdx.x;
  const int tx = tid & 15, ty = tid >> 4;
  float acc[4][4] = {};

  const int am  = tid >> 2;            // 0..63 : A row within tile
  const int ak0 = (tid & 3) * 4;       // 0,4,8,12
  const float* Arow = A + (size_t)(bm + am) * K;

  for (int k0 = 0; k0 < K; k0 += 16) {
    // stage A (transposed into [k][m])
    if (k0 + ak0 + 3 < K) {
      const float4 v = *reinterpret_cast<const float4*>(Arow + k0 + ak0);
      As[ak0 + 0][am] = v.x; As[ak0 + 1][am] = v.y;
      As[ak0 + 2][am] = v.z; As[ak0 + 3][am] = v.w;
    } else {
#pragma unroll
      for (int i = 0; i < 4; i++) {
        int k = k0 + ak0 + i;
        As[ak0 + i][am] = (k < K) ? Arow[k] : 0.f;
      }
    }
    // stage B
    if (!BT) {
      int kk = tid >> 4;               // 0..15
      int n0 = (tid & 15) * 4;         // 0..60
      float4 v = make_float4(0.f, 0.f, 0.f, 0.f);
      if (k0 + kk < K)
        v = *reinterpret_cast<const float4*>(B + (size_t)(k0 + kk) * N + bn + n0);
      *reinterpret_cast<float4*>(&Bs[kk][n0]) = v;
    } else {
      int n   = tid >> 2;              // 0..63
      int kk0 = (tid & 3) * 4;
      const float* Brow = B + (size_t)(bn + n) * K;
#pragma unroll
      for (int i = 0; i < 4; i++) {
        int k = k0 + kk0 + i;
        Bs[kk0 + i][n] = (k < K) ? Brow[k] : 0.f;
      }
    }
    __syncthreads();
#pragma unroll
    for (int kk = 0; kk < 16; kk++) {
      float4 a  = *reinterpret_cast<const float4*>(&As[kk][ty * 4]);
      float4 bv = *reinterpret_cast<const float4*>(&Bs[kk][tx * 4]);
      float av[4] = {a.x, a.y, a.z, a.w};
      float bb[4] = {bv.x, bv.y, bv.z, bv.w};
#pragma unroll
      for (int i = 0; i < 4; i++)
#pragma unroll
        for (int j = 0; j < 4; j++)
          acc[i][j] = fmaf(av[i], bb[j], acc[i][j]);
    }
    __syncthreads();
  }
  // epilogue
#pragma unroll
  for (int i = 0; i < 4; i++) {
    int row = bm + ty * 4 + i;
    size_t base = (size_t)row * N + bn + tx * 4;
#pragma unroll
    for (int j = 0; j < 4; j++) {
      float v = acc[i][j];
      if (bias) v += bias[bn + tx * 4 + j];
      if (GELU) v = 0.5f * v * (1.f + erff(v * 0.70710678118654752f));
      if (r1) v += r1[base + j];
      if (r2) v += r2[base + j];
      C[base + j] = v;
    }
  }
}

// ---------------- flash attention (online softmax), fp32 ----------------
// qkv: (Bn*Nn, 2304) with layout [s(3)][h(12)][d(64)] on last dim.
// out: (Bn*Nn, 768), channel = h*64+d.
// grid: (Bn*12, ceil(Nn/16)), block 256 = 16 q-rows x 16 lanes.
__global__ __launch_bounds__(256) void attn_k(const float* __restrict__ qkv,
                                              float* __restrict__ out,
                                              int Bn, int Nn) {
  const int b = blockIdx.x / NHEAD;
  const int h = blockIdx.x % NHEAD;
  const int q0 = blockIdx.y * 16;
  const int tid = threadIdx.x;
  const int row = tid >> 4;   // 0..15 local q row
  const int c   = tid & 15;   // lane within row

  __shared__ float Qs[16][65];
  __shared__ float Ks[32][65];
  __shared__ float Vs[32][65];
  __shared__ float Ps[16][32];

  {  // load Q tile (scaled by 1/8)
    int r  = tid >> 4;            // wait: need 16 rows x 64 dims = 1024 elems
    int d0 = (tid & 15) * 4;
    int n = q0 + r;
    float4 v = make_float4(0.f, 0.f, 0.f, 0.f);
    if (n < Nn)
      v = *reinterpret_cast<const float4*>(qkv + ((size_t)(b * Nn + n)) * 2304 + h * 64 + d0);
    Qs[r][d0] = v.x * 0.125f; Qs[r][d0 + 1] = v.y * 0.125f;
    Qs[r][d0 + 2] = v.z * 0.125f; Qs[r][d0 + 3] = v.w * 0.125f;
  }
  __syncthreads();

  float m = -1e30f, l = 0.f;
  float o0 = 0.f, o1 = 0.f, o2 = 0.f, o3 = 0.f;
  const int d0 = c * 4;

  for (int k0 = 0; k0 < Nn; k0 += 32) {
    {  // stage K,V tiles (32x64 each)
      int j  = tid >> 3;           // 0..31
      int dd = (tid & 7) * 8;      // 0..56
      int n = k0 + j;
      if (n < Nn) {
        const float4* kp = reinterpret_cast<const float4*>(
            qkv + ((size_t)(b * Nn + n)) * 2304 + 768 + h * 64 + dd);
        const float4* vp = reinterpret_cast<const float4*>(
            qkv + ((size_t)(b * Nn + n)) * 2304 + 1536 + h * 64 + dd);
        float4 ka = kp[0], kb = kp[1];
        float4 va = vp[0], vb = vp[1];
        Ks[j][dd + 0] = ka.x; Ks[j][dd + 1] = ka.y; Ks[j][dd + 2] = ka.z; Ks[j][dd + 3] = ka.w;
        Ks[j][dd + 4] = kb.x; Ks[j][dd + 5] = kb.y; Ks[j][dd + 6] = kb.z; Ks[j][dd + 7] = kb.w;
        Vs[j][dd + 0] = va.x; Vs[j][dd + 1] = va.y; Vs[j][dd + 2] = va.z; Vs[j][dd + 3] = va.w;
        Vs[j][dd + 4] = vb.x; Vs[j][dd + 5] = vb.y; Vs[j][dd + 6] = vb.z; Vs[j][dd + 7] = vb.w;
      } else {
#pragma unroll
        for (int q = 0; q < 8; q++) { Ks[j][dd + q] = 0.f; Vs[j][dd + q] = 0.f; }
      }
    }
    __syncthreads();

    // scores for keys j=c and j=c+16
    float s0 = 0.f, s1 = 0.f;
#pragma unroll 8
    for (int d = 0; d < 64; d++) {
      float qv = Qs[row][d];
      s0 = fmaf(qv, Ks[c][d], s0);
      s1 = fmaf(qv, Ks[c + 16][d], s1);
    }
    if (k0 + c >= Nn)      s0 = -1e30f;
    if (k0 + c + 16 >= Nn) s1 = -1e30f;

    float smax = fmaxf(s0, s1);
#pragma unroll
    for (int off = 8; off; off >>= 1) smax = fmaxf(smax, __shfl_xor(smax, off, 16));
    float mnew = fmaxf(m, smax);
    float scale = __expf(m - mnew);
    float p0 = __expf(s0 - mnew);
    float p1 = __expf(s1 - mnew);
    float ps = p0 + p1;
#pragma unroll
    for (int off = 8; off; off >>= 1) ps += __shfl_xor(ps, off, 16);
    l = l * scale + ps;
    m = mnew;
    o0 *= scale; o1 *= scale; o2 *= scale; o3 *= scale;
    Ps[row][c] = p0;
    Ps[row][c + 16] = p1;
    __syncthreads();

#pragma unroll 8
    for (int j = 0; j < 32; j++) {
      float p = Ps[row][j];
      o0 = fmaf(p, Vs[j][d0 + 0], o0);
      o1 = fmaf(p, Vs[j][d0 + 1], o1);
      o2 = fmaf(p, Vs[j][d0 + 2], o2);
      o3 = fmaf(p, Vs[j][d0 + 3], o3);
    }
    __syncthreads();
  }

  int n = q0 + row;
  if (n < Nn) {
    float inv = 1.f / l;
    float4 v = make_float4(o0 * inv, o1 * inv, o2 * inv, o3 * inv);
    *reinterpret_cast<float4*>(out + ((size_t)(b * Nn + n)) * DM + h * 64 + d0) = v;
  }
}

// ---------------- mean over sequence: (4,1184,768) -> (4,768) ----------------
__global__ __launch_bounds__(256) void mean_k(const float* __restrict__ X,
                                              float* __restrict__ out) {
  int b = blockIdx.x;
  int d = blockIdx.y * 256 + threadIdx.x;
  float s = 0.f;
  for (int r = 0; r < 1184; r++) s += X[((size_t)b * 1184 + r) * DM + d];
  out[b * DM + d] = s * (1.f / 1184.f);
}

// ---------------- orchestration ----------------
extern "C" void kernel_launch(void* const* d_in, const int* in_sizes, int n_in,
                              void* d_out, int out_size, void* d_ws, size_t ws_size,
                              hipStream_t stream) {
  (void)in_sizes; (void)n_in; (void)out_size; (void)ws_size;
  const float* x      = (const float*)d_in[0];
  const float* conv_w = (const float*)d_in[1];
  const float* conv_b = (const float*)d_in[2];
  const float* cls    = (const float*)d_in[3];
  const float* pos    = (const float*)d_in[4];
  const float* tpos   = (const float*)d_in[5];
  // per-prefix weights: 0 pre_g,1 pre_b,2 n1_g,3 n1_b,4 qkv_w,5 qkv_b,
  //                     6 proj_w,7 proj_b,8 n2_g,9 n2_b,10 fc1_w,11 fc1_b,12 fc2_w,13 fc2_b
  const float* W[2][14];
  for (int p = 0; p < 2; p++)
    for (int i = 0; i < 14; i++)
      W[p][i] = (const float*)d_in[6 + p * 14 + i];

  float* ws = (float*)d_ws;
  const size_t TOK = (size_t)NTOK * DM;   // 3,637,248 floats
  float* X   = ws;            // residual stream
  float* XN  = X + TOK;       // pre-norm output
  float* TA  = XN + TOK;      // LN-temp / attn-out / conv-out (aliased)
  float* Y   = TA + TOK;      // y buffer
  float* BIG = Y + TOK;       // qkv (4736x2304) / ffn hidden (4736x3072) / im2col (aliased)

  // ---- patch embedding ----
  im2col_k<<<10584, 256, 0, stream>>>(x, BIG);                 // 4608*588
  gemm_k<true, false><<<dim3(72, 12), 256, 0, stream>>>(
      BIG, conv_w, conv_b, nullptr, nullptr, TA, 4608, 768, 588);
  assemble_k<<<14208, 256, 0, stream>>>(TA, cls, pos, X);

  for (int phase = 0; phase < 2; phase++) {
    const int Bn = (phase == 0) ? 128 : 4;
    const int Nn = (phase == 0) ? 37 : 1184;
    if (phase == 1) tpos_k<<<14208, 256, 0, stream>>>(X, tpos);
    for (int i = 0; i < 3; i++) {
      const float* pre_g = W[phase][0] + i * DM;
      const float* pre_b = W[phase][1] + i * DM;
      const float* n1_g  = W[phase][2] + i * DM;
      const float* n1_b  = W[phase][3] + i * DM;
      const float* qkv_w = W[phase][4] + (size_t)i * DM * 2304;
      const float* qkv_b = W[phase][5] + i * 2304;
      const float* prj_w = W[phase][6] + (size_t)i * DM * DM;
      const float* prj_b = W[phase][7] + i * DM;
      const float* n2_g  = W[phase][8] + i * DM;
      const float* n2_b  = W[phase][9] + i * DM;
      const float* fc1_w = W[phase][10] + (size_t)i * DM * 3072;
      const float* fc1_b = W[phase][11] + i * 3072;
      const float* fc2_w = W[phase][12] + (size_t)i * 3072 * DM;
      const float* fc2_b = W[phase][13] + i * DM;

      ln_k<<<NTOK, 256, 0, stream>>>(X, pre_g, pre_b, XN);                 // xn
      ln_k<<<NTOK, 256, 0, stream>>>(XN, n1_g, n1_b, TA);                  // ln(xn)
      gemm_k<false, false><<<dim3(74, 36), 256, 0, stream>>>(              // qkv
          TA, qkv_w, qkv_b, nullptr, nullptr, BIG, NTOK, 2304, DM);
      attn_k<<<dim3(Bn * NHEAD, (Nn + 15) / 16), 256, 0, stream>>>(BIG, TA, Bn, Nn);
      gemm_k<false, false><<<dim3(74, 12), 256, 0, stream>>>(              // proj + xn
          TA, prj_w, prj_b, XN, nullptr, Y, NTOK, DM, DM);
      ln_k<<<NTOK, 256, 0, stream>>>(Y, n2_g, n2_b, TA);                   // ln(y)
      gemm_k<false, true><<<dim3(74, 48), 256, 0, stream>>>(               // fc1+gelu
          TA, fc1_w, fc1_b, nullptr, nullptr, BIG, NTOK, 3072, DM);
      gemm_k<false, false><<<dim3(74, 12), 256, 0, stream>>>(              // fc2 + y + x
          BIG, fc2_w, fc2_b, Y, X, X, NTOK, DM, 3072);
    }
  }
  mean_k<<<dim3(4, 3), 256, 0, stream>>>(X, (float*)d_out);
}

// Round 2
// 6690.850 us; speedup vs baseline: 1.3417x; 1.3417x over previous
//
#include <hip/hip_runtime.h>
#include <math.h>

// ---------------- constants ----------------
// B=4, T=32, IMG=84, P=14, D=768, H=12, L=3, GP=6, NP=36, N=37, FF=3072, HD=64
// tokens total = 4*32*37 = 4736 (both spatial flat and temporal flat)

#define NTOK 4736
#define DM   768
#define NHEAD 12

typedef __attribute__((ext_vector_type(8))) short bf16x8;
typedef __attribute__((ext_vector_type(4))) float f32x4;

__device__ inline short f2bf(float f) {
  union { float f; unsigned u; } v; v.f = f;
  unsigned r = v.u + 0x7FFF + ((v.u >> 16) & 1);   // RNE
  return (short)(r >> 16);
}

// ---------------- im2col: (128,3,84,84) -> (4608, 588) ----------------
__global__ __launch_bounds__(256) void im2col_k(const float* __restrict__ x,
                                                float* __restrict__ col) {
  int i = blockIdx.x * 256 + threadIdx.x;       // < 4608*588 = 2709504
  int r = i / 588, k = i % 588;
  int bt = r / 36, p = r % 36;
  int gy = p / 6, gx = p % 6;
  int c = k / 196, rem = k % 196;
  int ky = rem / 14, kx = rem % 14;
  col[i] = x[(((size_t)bt * 3 + c) * 84 + gy * 14 + ky) * 84 + gx * 14 + kx];
}

// ---------------- token assembly: cls + patches + pos ----------------
__global__ __launch_bounds__(256) void assemble_k(const float* __restrict__ conv_out,
                                                  const float* __restrict__ cls,
                                                  const float* __restrict__ pos,
                                                  float* __restrict__ X) {
  int i = blockIdx.x * 256 + threadIdx.x;       // < 4736*768
  int t = i / DM, d = i % DM;
  int bt = t / 37, n = t % 37;
  float v = (n == 0) ? cls[d] : conv_out[((size_t)bt * 36 + (n - 1)) * DM + d];
  X[i] = v + pos[n * DM + d];
}

// ---------------- temporal pos add ----------------
__global__ __launch_bounds__(256) void tpos_k(float* __restrict__ X,
                                              const float* __restrict__ tpos) {
  int i = blockIdx.x * 256 + threadIdx.x;       // < 4736*768
  int row = i / DM, d = i % DM;
  int tt = (row % 1184) / 37;                   // frame index 0..31
  X[i] += tpos[tt * DM + d];
}

// ---------------- LayerNorm over 768, one block per row ----------------
__global__ __launch_bounds__(256) void ln_k(const float* __restrict__ in,
                                            const float* __restrict__ g,
                                            const float* __restrict__ b,
                                            float* __restrict__ out) {
  int r = blockIdx.x;
  int tid = threadIdx.x;
  const float* xr = in + (size_t)r * DM;
  float v0 = xr[tid], v1 = xr[tid + 256], v2 = xr[tid + 512];
  float s  = v0 + v1 + v2;
  float sq = v0 * v0 + v1 * v1 + v2 * v2;
#pragma unroll
  for (int off = 32; off; off >>= 1) {
    s  += __shfl_down(s, off);
    sq += __shfl_down(sq, off);
  }
  __shared__ float ss[4], sg[4];
  if ((tid & 63) == 0) { ss[tid >> 6] = s; sg[tid >> 6] = sq; }
  __syncthreads();
  float S = ss[0] + ss[1] + ss[2] + ss[3];
  float Q = sg[0] + sg[1] + sg[2] + sg[3];
  float mean = S * (1.f / 768.f);
  float var  = Q * (1.f / 768.f) - mean * mean;
  float rs = rsqrtf(var + 1e-5f);
  float* o = out + (size_t)r * DM;
  o[tid]       = (v0 - mean) * rs * g[tid]       + b[tid];
  o[tid + 256] = (v1 - mean) * rs * g[tid + 256] + b[tid + 256];
  o[tid + 512] = (v2 - mean) * rs * g[tid + 512] + b[tid + 512];
}

// ---------------- generic fp32 GEMM: C = A(MxK) * B(KxN) [+bias][gelu][+r1][+r2]
// BT=true: B given as NxK row-major (conv weight). 64x64 tile, 4x4/thread.
template <bool BT, bool GELU>
__global__ __launch_bounds__(256) void gemm_k(const float* __restrict__ A,
                                              const float* __restrict__ B,
                                              const float* __restrict__ bias,
                                              const float* __restrict__ r1,
                                              const float* __restrict__ r2,
                                              float* __restrict__ C,
                                              int M, int N, int K) {
  __shared__ float As[16][68];
  __shared__ float Bs[16][68];
  const int bm = blockIdx.x * 64, bn = blockIdx.y * 64;
  const int tid = threadIdx.x;
  const int tx = tid & 15, ty = tid >> 4;
  float acc[4][4] = {};

  const int am  = tid >> 2;
  const int ak0 = (tid & 3) * 4;
  const float* Arow = A + (size_t)(bm + am) * K;

  for (int k0 = 0; k0 < K; k0 += 16) {
    if (k0 + ak0 + 3 < K) {
      const float4 v = *reinterpret_cast<const float4*>(Arow + k0 + ak0);
      As[ak0 + 0][am] = v.x; As[ak0 + 1][am] = v.y;
      As[ak0 + 2][am] = v.z; As[ak0 + 3][am] = v.w;
    } else {
#pragma unroll
      for (int i = 0; i < 4; i++) {
        int k = k0 + ak0 + i;
        As[ak0 + i][am] = (k < K) ? Arow[k] : 0.f;
      }
    }
    if (!BT) {
      int kk = tid >> 4;
      int n0 = (tid & 15) * 4;
      float4 v = make_float4(0.f, 0.f, 0.f, 0.f);
      if (k0 + kk < K)
        v = *reinterpret_cast<const float4*>(B + (size_t)(k0 + kk) * N + bn + n0);
      *reinterpret_cast<float4*>(&Bs[kk][n0]) = v;
    } else {
      int n   = tid >> 2;
      int kk0 = (tid & 3) * 4;
      const float* Brow = B + (size_t)(bn + n) * K;
#pragma unroll
      for (int i = 0; i < 4; i++) {
        int k = k0 + kk0 + i;
        Bs[kk0 + i][n] = (k < K) ? Brow[k] : 0.f;
      }
    }
    __syncthreads();
#pragma unroll
    for (int kk = 0; kk < 16; kk++) {
      float4 a  = *reinterpret_cast<const float4*>(&As[kk][ty * 4]);
      float4 bv = *reinterpret_cast<const float4*>(&Bs[kk][tx * 4]);
      float av[4] = {a.x, a.y, a.z, a.w};
      float bb[4] = {bv.x, bv.y, bv.z, bv.w};
#pragma unroll
      for (int i = 0; i < 4; i++)
#pragma unroll
        for (int j = 0; j < 4; j++)
          acc[i][j] = fmaf(av[i], bb[j], acc[i][j]);
    }
    __syncthreads();
  }
#pragma unroll
  for (int i = 0; i < 4; i++) {
    int row = bm + ty * 4 + i;
    size_t base = (size_t)row * N + bn + tx * 4;
#pragma unroll
    for (int j = 0; j < 4; j++) {
      float v = acc[i][j];
      if (bias) v += bias[bn + tx * 4 + j];
      if (GELU) v = 0.5f * v * (1.f + erff(v * 0.70710678118654752f));
      if (r1) v += r1[base + j];
      if (r2) v += r2[base + j];
      C[base + j] = v;
    }
  }
}

// ---------------- MFMA bf16 flash attention ----------------
// qkv: (Bn*Nn, 2304), last-dim layout [s(3)][h(12)][d(64)].  out: (Bn*Nn, 768).
// grid: (Bn*12, ceil(Nn/64)); block 256 = 4 waves, each wave owns 16 q-rows.
// MFMA 16x16x32 bf16: A row=lane&15, k=(lane>>4)*8+j ; B col=lane&15, same k;
// C/D col=lane&15, row=(lane>>4)*4+reg (HW-verified layout).
__global__ __launch_bounds__(256) void attn_k(const float* __restrict__ qkv,
                                              float* __restrict__ out,
                                              int Bn, int Nn) {
  const int b = blockIdx.x / NHEAD, h = blockIdx.x % NHEAD;
  const int q0 = blockIdx.y * 64;
  const int tid = threadIdx.x;
  const int wid = tid >> 6, lane = tid & 63;
  const int lr = lane & 15, lg = lane >> 4;

  __shared__ short Ks[32][40];        // K tile [key][d], rows padded to 80B
  __shared__ short Vt[64][40];        // V tile transposed [d][key]
  __shared__ short Ps[4][16][40];     // per-wave P tile [qrow][key]

  // ---- Q fragments (A-operand rows = lr), scaled by 1/8 ----
  const int qrow_in = q0 + wid * 16 + lr;
  const int qcl = (qrow_in < Nn) ? qrow_in : (Nn - 1);
  const float* qp = qkv + ((size_t)(b * Nn + qcl)) * 2304 + h * 64 + lg * 8;
  bf16x8 qa0, qa1;
  {
    float4 x0 = *reinterpret_cast<const float4*>(qp);
    float4 x1 = *reinterpret_cast<const float4*>(qp + 4);
    float4 y0 = *reinterpret_cast<const float4*>(qp + 32);
    float4 y1 = *reinterpret_cast<const float4*>(qp + 36);
    float xv[8] = {x0.x, x0.y, x0.z, x0.w, x1.x, x1.y, x1.z, x1.w};
    float yv[8] = {y0.x, y0.y, y0.z, y0.w, y1.x, y1.y, y1.z, y1.w};
#pragma unroll
    for (int j = 0; j < 8; j++) {
      qa0[j] = f2bf(xv[j] * 0.125f);
      qa1[j] = f2bf(yv[j] * 0.125f);
    }
  }

  f32x4 oo[4];
#pragma unroll
  for (int dg = 0; dg < 4; dg++) oo[dg] = (f32x4){0.f, 0.f, 0.f, 0.f};
  float mm[4] = {-1e30f, -1e30f, -1e30f, -1e30f};
  float ll[4] = {0.f, 0.f, 0.f, 0.f};

  const int skey = tid >> 3;          // 0..31 staging key
  const int sd   = (tid & 7) * 8;     // 0..56 staging d-offset

  for (int k0 = 0; k0 < Nn; k0 += 32) {
    {  // ---- stage K (row-major bf16) and V (transposed bf16) ----
      int kg = k0 + skey; if (kg >= Nn) kg = Nn - 1;
      const float* kp = qkv + ((size_t)(b * Nn + kg)) * 2304 + 768 + h * 64 + sd;
      float4 a0 = *reinterpret_cast<const float4*>(kp);
      float4 a1 = *reinterpret_cast<const float4*>(kp + 4);
      float4 v0 = *reinterpret_cast<const float4*>(kp + 768);
      float4 v1 = *reinterpret_cast<const float4*>(kp + 772);
      float kv[8] = {a0.x, a0.y, a0.z, a0.w, a1.x, a1.y, a1.z, a1.w};
      float vv[8] = {v0.x, v0.y, v0.z, v0.w, v1.x, v1.y, v1.z, v1.w};
      bf16x8 kpack;
#pragma unroll
      for (int i = 0; i < 8; i++) kpack[i] = f2bf(kv[i]);
      *reinterpret_cast<bf16x8*>(&Ks[skey][sd]) = kpack;
#pragma unroll
      for (int i = 0; i < 8; i++) Vt[sd + i][skey] = f2bf(vv[i]);
    }
    __syncthreads();

    // ---- QK^T: S(16x32) via 4 MFMAs ----
    f32x4 c0 = (f32x4){0.f, 0.f, 0.f, 0.f};
    f32x4 c1 = (f32x4){0.f, 0.f, 0.f, 0.f};
    {
      bf16x8 kb;
      kb = *reinterpret_cast<const bf16x8*>(&Ks[lr][lg * 8]);
      c0 = __builtin_amdgcn_mfma_f32_16x16x32_bf16(qa0, kb, c0, 0, 0, 0);
      kb = *reinterpret_cast<const bf16x8*>(&Ks[lr][32 + lg * 8]);
      c0 = __builtin_amdgcn_mfma_f32_16x16x32_bf16(qa1, kb, c0, 0, 0, 0);
      kb = *reinterpret_cast<const bf16x8*>(&Ks[16 + lr][lg * 8]);
      c1 = __builtin_amdgcn_mfma_f32_16x16x32_bf16(qa0, kb, c1, 0, 0, 0);
      kb = *reinterpret_cast<const bf16x8*>(&Ks[16 + lr][32 + lg * 8]);
      c1 = __builtin_amdgcn_mfma_f32_16x16x32_bf16(qa1, kb, c1, 0, 0, 0);
    }

    if (k0 + 32 > Nn) {  // mask OOB keys (tail tile only)
      if (k0 + lr >= Nn)      { c0[0] = c0[1] = c0[2] = c0[3] = -1e30f; }
      if (k0 + 16 + lr >= Nn) { c1[0] = c1[1] = c1[2] = c1[3] = -1e30f; }
    }

    // ---- online softmax (per C-row = lg*4+r, keys spread over lr lanes) ----
#pragma unroll
    for (int r = 0; r < 4; r++) {
      float t = fmaxf(c0[r], c1[r]);
      t = fmaxf(t, __shfl_xor(t, 1, 16));
      t = fmaxf(t, __shfl_xor(t, 2, 16));
      t = fmaxf(t, __shfl_xor(t, 4, 16));
      t = fmaxf(t, __shfl_xor(t, 8, 16));
      float mn = fmaxf(mm[r], t);
      float sc = __expf(mm[r] - mn);
      float p0 = __expf(c0[r] - mn);
      float p1 = __expf(c1[r] - mn);
      float ps = p0 + p1;
      ps += __shfl_xor(ps, 1, 16);
      ps += __shfl_xor(ps, 2, 16);
      ps += __shfl_xor(ps, 4, 16);
      ps += __shfl_xor(ps, 8, 16);
      ll[r] = ll[r] * sc + ps;
      mm[r] = mn;
      oo[0][r] *= sc; oo[1][r] *= sc; oo[2][r] *= sc; oo[3][r] *= sc;
      Ps[wid][lg * 4 + r][lr]      = f2bf(p0);
      Ps[wid][lg * 4 + r][16 + lr] = f2bf(p1);
    }

    // ---- PV: O += P(16x32) * V(32x64) via 4 MFMAs ----
    {
      bf16x8 pa = *reinterpret_cast<const bf16x8*>(&Ps[wid][lr][lg * 8]);
#pragma unroll
      for (int dg = 0; dg < 4; dg++) {
        bf16x8 vb = *reinterpret_cast<const bf16x8*>(&Vt[dg * 16 + lr][lg * 8]);
        oo[dg] = __builtin_amdgcn_mfma_f32_16x16x32_bf16(pa, vb, oo[dg], 0, 0, 0);
      }
    }
    __syncthreads();
  }

  // ---- store: row = lg*4+r, col = dg*16+lr ----
#pragma unroll
  for (int r = 0; r < 4; r++) {
    int qr = q0 + wid * 16 + lg * 4 + r;
    if (qr < Nn) {
      float inv = 1.f / ll[r];
      float* op = out + ((size_t)(b * Nn + qr)) * DM + h * 64 + lr;
      op[0]  = oo[0][r] * inv;
      op[16] = oo[1][r] * inv;
      op[32] = oo[2][r] * inv;
      op[48] = oo[3][r] * inv;
    }
  }
}

// ---------------- mean over sequence: (4,1184,768) -> (4,768) ----------------
__global__ __launch_bounds__(256) void mean_k(const float* __restrict__ X,
                                              float* __restrict__ out) {
  int b = blockIdx.x;
  int d = blockIdx.y * 256 + threadIdx.x;
  float s = 0.f;
  for (int r = 0; r < 1184; r++) s += X[((size_t)b * 1184 + r) * DM + d];
  out[b * DM + d] = s * (1.f / 1184.f);
}

// ---------------- orchestration ----------------
extern "C" void kernel_launch(void* const* d_in, const int* in_sizes, int n_in,
                              void* d_out, int out_size, void* d_ws, size_t ws_size,
                              hipStream_t stream) {
  (void)in_sizes; (void)n_in; (void)out_size; (void)ws_size;
  const float* x      = (const float*)d_in[0];
  const float* conv_w = (const float*)d_in[1];
  const float* conv_b = (const float*)d_in[2];
  const float* cls    = (const float*)d_in[3];
  const float* pos    = (const float*)d_in[4];
  const float* tpos   = (const float*)d_in[5];
  const float* W[2][14];
  for (int p = 0; p < 2; p++)
    for (int i = 0; i < 14; i++)
      W[p][i] = (const float*)d_in[6 + p * 14 + i];

  float* ws = (float*)d_ws;
  const size_t TOK = (size_t)NTOK * DM;
  float* X   = ws;
  float* XN  = X + TOK;
  float* TA  = XN + TOK;
  float* Y   = TA + TOK;
  float* BIG = Y + TOK;

  // ---- patch embedding ----
  im2col_k<<<10584, 256, 0, stream>>>(x, BIG);
  gemm_k<true, false><<<dim3(72, 12), 256, 0, stream>>>(
      BIG, conv_w, conv_b, nullptr, nullptr, TA, 4608, 768, 588);
  assemble_k<<<14208, 256, 0, stream>>>(TA, cls, pos, X);

  for (int phase = 0; phase < 2; phase++) {
    const int Bn = (phase == 0) ? 128 : 4;
    const int Nn = (phase == 0) ? 37 : 1184;
    if (phase == 1) tpos_k<<<14208, 256, 0, stream>>>(X, tpos);
    for (int i = 0; i < 3; i++) {
      const float* pre_g = W[phase][0] + i * DM;
      const float* pre_b = W[phase][1] + i * DM;
      const float* n1_g  = W[phase][2] + i * DM;
      const float* n1_b  = W[phase][3] + i * DM;
      const float* qkv_w = W[phase][4] + (size_t)i * DM * 2304;
      const float* qkv_b = W[phase][5] + i * 2304;
      const float* prj_w = W[phase][6] + (size_t)i * DM * DM;
      const float* prj_b = W[phase][7] + i * DM;
      const float* n2_g  = W[phase][8] + i * DM;
      const float* n2_b  = W[phase][9] + i * DM;
      const float* fc1_w = W[phase][10] + (size_t)i * DM * 3072;
      const float* fc1_b = W[phase][11] + i * 3072;
      const float* fc2_w = W[phase][12] + (size_t)i * 3072 * DM;
      const float* fc2_b = W[phase][13] + i * DM;

      ln_k<<<NTOK, 256, 0, stream>>>(X, pre_g, pre_b, XN);
      ln_k<<<NTOK, 256, 0, stream>>>(XN, n1_g, n1_b, TA);
      gemm_k<false, false><<<dim3(74, 36), 256, 0, stream>>>(
          TA, qkv_w, qkv_b, nullptr, nullptr, BIG, NTOK, 2304, DM);
      attn_k<<<dim3(Bn * NHEAD, (Nn + 63) / 64), 256, 0, stream>>>(BIG, TA, Bn, Nn);
      gemm_k<false, false><<<dim3(74, 12), 256, 0, stream>>>(
          TA, prj_w, prj_b, XN, nullptr, Y, NTOK, DM, DM);
      ln_k<<<NTOK, 256, 0, stream>>>(Y, n2_g, n2_b, TA);
      gemm_k<false, true><<<dim3(74, 48), 256, 0, stream>>>(
          TA, fc1_w, fc1_b, nullptr, nullptr, BIG, NTOK, 3072, DM);
      gemm_k<false, false><<<dim3(74, 12), 256, 0, stream>>>(
          BIG, fc2_w, fc2_b, Y, X, X, NTOK, DM, 3072);
    }
  }
  mean_k<<<dim3(4, 3), 256, 0, stream>>>(X, (float*)d_out);
}

// Round 3
// 2666.288 us; speedup vs baseline: 3.3668x; 2.5094x over previous
//
#include <hip/hip_runtime.h>
#include <math.h>

// ---------------- constants ----------------
// B=4, T=32, IMG=84, P=14, D=768, H=12, L=3, GP=6, NP=36, N=37, FF=3072, HD=64
#define NTOK 4736
#define DM   768
#define NHEAD 12
#define KC   608          // conv K padded (588 -> 608, multiple of 32)

typedef __attribute__((ext_vector_type(8))) short bf16x8;
typedef __attribute__((ext_vector_type(4))) float f32x4;

__device__ inline short f2bf(float f) {
  union { float f; unsigned u; } v; v.f = f;
  unsigned r = v.u + 0x7FFF + ((v.u >> 16) & 1);   // RNE
  return (short)(r >> 16);
}

__device__ inline void gload16(const void* g, void* l) {
  __builtin_amdgcn_global_load_lds(
      (const __attribute__((address_space(1))) void*)g,
      (__attribute__((address_space(3))) void*)l, 16, 0, 0);
}

// ---------------- im2col: (128,3,84,84) fp32 -> (4608, 608) bf16, zero-pad ----
__global__ __launch_bounds__(256) void im2col_k(const float* __restrict__ x,
                                                short* __restrict__ col) {
  int i = blockIdx.x * 256 + threadIdx.x;       // < 4608*608
  int r = i / KC, k = i % KC;
  short v = 0;
  if (k < 588) {
    int bt = r / 36, p = r % 36;
    int gy = p / 6, gx = p % 6;
    int c = k / 196, rem = k % 196;
    int ky = rem / 14, kx = rem % 14;
    v = f2bf(x[(((size_t)bt * 3 + c) * 84 + gy * 14 + ky) * 84 + gx * 14 + kx]);
  }
  col[i] = v;
}

// ---------------- conv weight: (768,588) fp32 -> (768,608) bf16 zero-pad ------
__global__ __launch_bounds__(256) void convw_k(const float* __restrict__ w,
                                               short* __restrict__ out) {
  int i = blockIdx.x * 256 + threadIdx.x;       // < 768*608
  int n = i / KC, k = i % KC;
  out[i] = (k < 588) ? f2bf(w[(size_t)n * 588 + k]) : (short)0;
}

// ---------------- weight transpose+convert: (L,K,N) fp32 -> (L,N,K) bf16 ------
__global__ __launch_bounds__(256) void wt_k(const float* __restrict__ in,
                                            short* __restrict__ out,
                                            int K, int N) {
  __shared__ float tile[32][33];
  const int l = blockIdx.z;
  in  += (size_t)l * K * N;
  out += (size_t)l * N * K;
  const int n0 = blockIdx.x * 32, k0 = blockIdx.y * 32;
  const int tx = threadIdx.x & 31, ty = threadIdx.x >> 5;   // ty 0..7
#pragma unroll
  for (int r = 0; r < 4; r++)
    tile[ty + 8 * r][tx] = in[(size_t)(k0 + ty + 8 * r) * N + n0 + tx];
  __syncthreads();
#pragma unroll
  for (int r = 0; r < 4; r++)
    out[(size_t)(n0 + ty + 8 * r) * K + k0 + tx] = f2bf(tile[tx][ty + 8 * r]);
}

// ---------------- token assembly: cls + patches + pos (fp32) ----------------
__global__ __launch_bounds__(256) void assemble_k(const float* __restrict__ conv_out,
                                                  const float* __restrict__ cls,
                                                  const float* __restrict__ pos,
                                                  float* __restrict__ X) {
  int i = blockIdx.x * 256 + threadIdx.x;       // < 4736*768
  int t = i / DM, d = i % DM;
  int bt = t / 37, n = t % 37;
  float v = (n == 0) ? cls[d] : conv_out[((size_t)bt * 36 + (n - 1)) * DM + d];
  X[i] = v + pos[n * DM + d];
}

// ---------------- temporal pos add ----------------
__global__ __launch_bounds__(256) void tpos_k(float* __restrict__ X,
                                              const float* __restrict__ tpos) {
  int i = blockIdx.x * 256 + threadIdx.x;
  int row = i / DM, d = i % DM;
  int tt = (row % 1184) / 37;
  X[i] += tpos[tt * DM + d];
}

// ---------------- LayerNorm over 768; template output dtype ----------------
template <bool OBF>
__global__ __launch_bounds__(256) void ln_k(const float* __restrict__ in,
                                            const float* __restrict__ g,
                                            const float* __restrict__ b,
                                            void* __restrict__ outp) {
  int r = blockIdx.x;
  int tid = threadIdx.x;
  const float* xr = in + (size_t)r * DM;
  float v0 = xr[tid], v1 = xr[tid + 256], v2 = xr[tid + 512];
  float s  = v0 + v1 + v2;
  float sq = v0 * v0 + v1 * v1 + v2 * v2;
#pragma unroll
  for (int off = 32; off; off >>= 1) {
    s  += __shfl_down(s, off);
    sq += __shfl_down(sq, off);
  }
  __shared__ float ss[4], sg[4];
  if ((tid & 63) == 0) { ss[tid >> 6] = s; sg[tid >> 6] = sq; }
  __syncthreads();
  float S = ss[0] + ss[1] + ss[2] + ss[3];
  float Q = sg[0] + sg[1] + sg[2] + sg[3];
  float mean = S * (1.f / 768.f);
  float var  = Q * (1.f / 768.f) - mean * mean;
  float rs = rsqrtf(var + 1e-5f);
  float o0 = (v0 - mean) * rs * g[tid]       + b[tid];
  float o1 = (v1 - mean) * rs * g[tid + 256] + b[tid + 256];
  float o2 = (v2 - mean) * rs * g[tid + 512] + b[tid + 512];
  if (OBF) {
    short* o = (short*)outp + (size_t)r * DM;
    o[tid] = f2bf(o0); o[tid + 256] = f2bf(o1); o[tid + 512] = f2bf(o2);
  } else {
    float* o = (float*)outp + (size_t)r * DM;
    o[tid] = o0; o[tid + 256] = o1; o[tid + 512] = o2;
  }
}

// ---------------- fused double LayerNorm: xn = LN(x,pre) [fp32], w = LN(xn,n1) [bf16]
__global__ __launch_bounds__(256) void ln2_k(const float* __restrict__ in,
                                             const float* __restrict__ g1,
                                             const float* __restrict__ b1,
                                             const float* __restrict__ g2,
                                             const float* __restrict__ b2,
                                             float* __restrict__ xn,
                                             short* __restrict__ w) {
  int r = blockIdx.x;
  int tid = threadIdx.x;
  const float* xr = in + (size_t)r * DM;
  float v0 = xr[tid], v1 = xr[tid + 256], v2 = xr[tid + 512];
  float s  = v0 + v1 + v2;
  float sq = v0 * v0 + v1 * v1 + v2 * v2;
#pragma unroll
  for (int off = 32; off; off >>= 1) {
    s  += __shfl_down(s, off);
    sq += __shfl_down(sq, off);
  }
  __shared__ float ss[4], sg[4], ss2[4], sg2[4];
  if ((tid & 63) == 0) { ss[tid >> 6] = s; sg[tid >> 6] = sq; }
  __syncthreads();
  float S = ss[0] + ss[1] + ss[2] + ss[3];
  float Q = sg[0] + sg[1] + sg[2] + sg[3];
  float mean = S * (1.f / 768.f);
  float var  = Q * (1.f / 768.f) - mean * mean;
  float rs = rsqrtf(var + 1e-5f);
  float x0 = (v0 - mean) * rs * g1[tid]       + b1[tid];
  float x1 = (v1 - mean) * rs * g1[tid + 256] + b1[tid + 256];
  float x2 = (v2 - mean) * rs * g1[tid + 512] + b1[tid + 512];
  float* xo = xn + (size_t)r * DM;
  xo[tid] = x0; xo[tid + 256] = x1; xo[tid + 512] = x2;
  // second LN
  float s2  = x0 + x1 + x2;
  float sq2 = x0 * x0 + x1 * x1 + x2 * x2;
#pragma unroll
  for (int off = 32; off; off >>= 1) {
    s2  += __shfl_down(s2, off);
    sq2 += __shfl_down(sq2, off);
  }
  if ((tid & 63) == 0) { ss2[tid >> 6] = s2; sg2[tid >> 6] = sq2; }
  __syncthreads();
  float S2 = ss2[0] + ss2[1] + ss2[2] + ss2[3];
  float Q2 = sg2[0] + sg2[1] + sg2[2] + sg2[3];
  float mean2 = S2 * (1.f / 768.f);
  float var2  = Q2 * (1.f / 768.f) - mean2 * mean2;
  float rs2 = rsqrtf(var2 + 1e-5f);
  short* wo = w + (size_t)r * DM;
  wo[tid]       = f2bf((x0 - mean2) * rs2 * g2[tid]       + b2[tid]);
  wo[tid + 256] = f2bf((x1 - mean2) * rs2 * g2[tid + 256] + b2[tid + 256]);
  wo[tid + 512] = f2bf((x2 - mean2) * rs2 * g2[tid + 512] + b2[tid + 512]);
}

// ---------------- MFMA bf16 GEMM: C = A(MxK) * B^T(NxK) [+bias][gelu][+r1][+r2]
// A, Bw bf16 row-major (K-contiguous). 128x128 tile, 4 waves (2x2), BK=32.
// LDS plane layout [k/8][row][8]: gload_lds linear write == row order; b128 reads
// bank-balanced. Requires M%128==0, N%128==0, K%32==0 (all shapes satisfy).
template <bool GELU, bool OBF, bool HASR1, bool HASR2>
__global__ __launch_bounds__(256) void mgemm_k(const short* __restrict__ A,
                                               const short* __restrict__ Bw,
                                               const float* __restrict__ bias,
                                               const float* __restrict__ r1,
                                               const float* __restrict__ r2,
                                               void* __restrict__ Cout,
                                               int M, int N, int K) {
  __shared__ short As[4][128][8];
  __shared__ short Bs[4][128][8];
  const int bm = blockIdx.x * 128, bn = blockIdx.y * 128;
  const int tid = threadIdx.x, wid = tid >> 6, lane = tid & 63;
  const int lr = lane & 15, lg = lane >> 4;
  const int wm = (wid >> 1) * 64, wn = (wid & 1) * 64;

  f32x4 acc[4][4];
#pragma unroll
  for (int m = 0; m < 4; m++)
#pragma unroll
    for (int n = 0; n < 4; n++) acc[m][n] = (f32x4){0.f, 0.f, 0.f, 0.f};

  const short* Ab = A  + (size_t)bm * K + wid * 8;
  const short* Bb = Bw + (size_t)bn * K + wid * 8;

  for (int k0 = 0; k0 < K; k0 += 32) {
    // wave `wid` stages k-plane `wid` (k = k0+wid*8 .. +7) for all 128 rows.
    gload16(Ab + (size_t)lane * K + k0,        &As[wid][0][0]);
    gload16(Ab + (size_t)(lane + 64) * K + k0, &As[wid][64][0]);
    gload16(Bb + (size_t)lane * K + k0,        &Bs[wid][0][0]);
    gload16(Bb + (size_t)(lane + 64) * K + k0, &Bs[wid][64][0]);
    __syncthreads();

    bf16x8 af[4], bfr[4];
#pragma unroll
    for (int m = 0; m < 4; m++)
      af[m] = *reinterpret_cast<const bf16x8*>(&As[lg][wm + m * 16 + lr][0]);
#pragma unroll
    for (int n = 0; n < 4; n++)
      bfr[n] = *reinterpret_cast<const bf16x8*>(&Bs[lg][wn + n * 16 + lr][0]);
#pragma unroll
    for (int m = 0; m < 4; m++)
#pragma unroll
      for (int n = 0; n < 4; n++)
        acc[m][n] = __builtin_amdgcn_mfma_f32_16x16x32_bf16(af[m], bfr[n], acc[m][n], 0, 0, 0);
    __syncthreads();
  }

  // epilogue: row = bm+wm+m*16+lg*4+r, col = bn+wn+n*16+lr
#pragma unroll
  for (int m = 0; m < 4; m++) {
#pragma unroll
    for (int r = 0; r < 4; r++) {
      int row = bm + wm + m * 16 + lg * 4 + r;
#pragma unroll
      for (int n = 0; n < 4; n++) {
        int col = bn + wn + n * 16 + lr;
        size_t idx = (size_t)row * N + col;
        float v = acc[m][n][r];
        if (bias) v += bias[col];
        if (GELU) v = 0.5f * v * (1.f + erff(v * 0.70710678118654752f));
        if (HASR1) v += r1[idx];
        if (HASR2) v += r2[idx];
        if (OBF) ((short*)Cout)[idx] = f2bf(v);
        else     ((float*)Cout)[idx] = v;
      }
    }
  }
}

// ---------------- MFMA bf16 flash attention (bf16 qkv in, bf16 out) ----------
// qkv: (Bn*Nn, 2304) bf16, layout [s(3)][h(12)][d(64)].  out: (Bn*Nn, 768) bf16.
// grid: (Bn*12, ceil(Nn/64)); block 256 = 4 waves, each wave owns 16 q-rows.
__global__ __launch_bounds__(256) void attn_k(const short* __restrict__ qkv,
                                              short* __restrict__ out,
                                              int Bn, int Nn) {
  const int b = blockIdx.x / NHEAD, h = blockIdx.x % NHEAD;
  const int q0 = blockIdx.y * 64;
  const int tid = threadIdx.x;
  const int wid = tid >> 6, lane = tid & 63;
  const int lr = lane & 15, lg = lane >> 4;

  __shared__ short Ks[32][40];
  __shared__ short Vt[64][40];
  __shared__ short Ps[4][16][40];

  const int qrow_in = q0 + wid * 16 + lr;
  const int qcl = (qrow_in < Nn) ? qrow_in : (Nn - 1);
  const short* qp = qkv + ((size_t)(b * Nn + qcl)) * 2304 + h * 64 + lg * 8;
  bf16x8 qa0 = *reinterpret_cast<const bf16x8*>(qp);
  bf16x8 qa1 = *reinterpret_cast<const bf16x8*>(qp + 32);

  f32x4 oo[4];
#pragma unroll
  for (int dg = 0; dg < 4; dg++) oo[dg] = (f32x4){0.f, 0.f, 0.f, 0.f};
  float mm[4] = {-1e30f, -1e30f, -1e30f, -1e30f};
  float ll[4] = {0.f, 0.f, 0.f, 0.f};

  const int skey = tid >> 3;
  const int sd   = (tid & 7) * 8;

  for (int k0 = 0; k0 < Nn; k0 += 32) {
    {
      int kg = k0 + skey; if (kg >= Nn) kg = Nn - 1;
      const short* kp = qkv + ((size_t)(b * Nn + kg)) * 2304 + 768 + h * 64 + sd;
      bf16x8 kv = *reinterpret_cast<const bf16x8*>(kp);
      bf16x8 vv = *reinterpret_cast<const bf16x8*>(kp + 768);
      *reinterpret_cast<bf16x8*>(&Ks[skey][sd]) = kv;
#pragma unroll
      for (int i = 0; i < 8; i++) Vt[sd + i][skey] = vv[i];
    }
    __syncthreads();

    f32x4 c0 = (f32x4){0.f, 0.f, 0.f, 0.f};
    f32x4 c1 = (f32x4){0.f, 0.f, 0.f, 0.f};
    {
      bf16x8 kb;
      kb = *reinterpret_cast<const bf16x8*>(&Ks[lr][lg * 8]);
      c0 = __builtin_amdgcn_mfma_f32_16x16x32_bf16(qa0, kb, c0, 0, 0, 0);
      kb = *reinterpret_cast<const bf16x8*>(&Ks[lr][32 + lg * 8]);
      c0 = __builtin_amdgcn_mfma_f32_16x16x32_bf16(qa1, kb, c0, 0, 0, 0);
      kb = *reinterpret_cast<const bf16x8*>(&Ks[16 + lr][lg * 8]);
      c1 = __builtin_amdgcn_mfma_f32_16x16x32_bf16(qa0, kb, c1, 0, 0, 0);
      kb = *reinterpret_cast<const bf16x8*>(&Ks[16 + lr][32 + lg * 8]);
      c1 = __builtin_amdgcn_mfma_f32_16x16x32_bf16(qa1, kb, c1, 0, 0, 0);
    }
#pragma unroll
    for (int r = 0; r < 4; r++) { c0[r] *= 0.125f; c1[r] *= 0.125f; }

    if (k0 + 32 > Nn) {
      if (k0 + lr >= Nn)      { c0[0] = c0[1] = c0[2] = c0[3] = -1e30f; }
      if (k0 + 16 + lr >= Nn) { c1[0] = c1[1] = c1[2] = c1[3] = -1e30f; }
    }

#pragma unroll
    for (int r = 0; r < 4; r++) {
      float t = fmaxf(c0[r], c1[r]);
      t = fmaxf(t, __shfl_xor(t, 1, 16));
      t = fmaxf(t, __shfl_xor(t, 2, 16));
      t = fmaxf(t, __shfl_xor(t, 4, 16));
      t = fmaxf(t, __shfl_xor(t, 8, 16));
      float mn = fmaxf(mm[r], t);
      float sc = __expf(mm[r] - mn);
      float p0 = __expf(c0[r] - mn);
      float p1 = __expf(c1[r] - mn);
      float ps = p0 + p1;
      ps += __shfl_xor(ps, 1, 16);
      ps += __shfl_xor(ps, 2, 16);
      ps += __shfl_xor(ps, 4, 16);
      ps += __shfl_xor(ps, 8, 16);
      ll[r] = ll[r] * sc + ps;
      mm[r] = mn;
      oo[0][r] *= sc; oo[1][r] *= sc; oo[2][r] *= sc; oo[3][r] *= sc;
      Ps[wid][lg * 4 + r][lr]      = f2bf(p0);
      Ps[wid][lg * 4 + r][16 + lr] = f2bf(p1);
    }

    {
      bf16x8 pa = *reinterpret_cast<const bf16x8*>(&Ps[wid][lr][lg * 8]);
#pragma unroll
      for (int dg = 0; dg < 4; dg++) {
        bf16x8 vb = *reinterpret_cast<const bf16x8*>(&Vt[dg * 16 + lr][lg * 8]);
        oo[dg] = __builtin_amdgcn_mfma_f32_16x16x32_bf16(pa, vb, oo[dg], 0, 0, 0);
      }
    }
    __syncthreads();
  }

#pragma unroll
  for (int r = 0; r < 4; r++) {
    int qr = q0 + wid * 16 + lg * 4 + r;
    if (qr < Nn) {
      float inv = 1.f / ll[r];
      short* op = out + ((size_t)(b * Nn + qr)) * DM + h * 64 + lr;
      op[0]  = f2bf(oo[0][r] * inv);
      op[16] = f2bf(oo[1][r] * inv);
      op[32] = f2bf(oo[2][r] * inv);
      op[48] = f2bf(oo[3][r] * inv);
    }
  }
}

// ---------------- mean over sequence: (4,1184,768) -> (4,768) ----------------
__global__ __launch_bounds__(256) void mean_k(const float* __restrict__ X,
                                              float* __restrict__ out) {
  int b = blockIdx.x;
  int d = blockIdx.y * 256 + threadIdx.x;
  float s = 0.f;
  for (int r = 0; r < 1184; r++) s += X[((size_t)b * 1184 + r) * DM + d];
  out[b * DM + d] = s * (1.f / 1184.f);
}

// ---------------- orchestration ----------------
extern "C" void kernel_launch(void* const* d_in, const int* in_sizes, int n_in,
                              void* d_out, int out_size, void* d_ws, size_t ws_size,
                              hipStream_t stream) {
  (void)in_sizes; (void)n_in; (void)out_size; (void)ws_size;
  const float* x      = (const float*)d_in[0];
  const float* conv_w = (const float*)d_in[1];
  const float* conv_b = (const float*)d_in[2];
  const float* cls    = (const float*)d_in[3];
  const float* pos    = (const float*)d_in[4];
  const float* tpos   = (const float*)d_in[5];
  const float* W[2][14];
  for (int p = 0; p < 2; p++)
    for (int i = 0; i < 14; i++)
      W[p][i] = (const float*)d_in[6 + p * 14 + i];

  char* ws = (char*)d_ws;
  const size_t TOKF = (size_t)NTOK * DM * 4;          // fp32 token buffer bytes
  const size_t TOKH = (size_t)NTOK * DM * 2;          // bf16 token buffer bytes
  float* X    = (float*)(ws);                          // residual, fp32
  float* XN   = (float*)(ws + TOKF);                   // pre-norm, fp32
  float* Y    = (float*)(ws + 2 * TOKF);               // y / conv-out alias, fp32
  short* TA2  = (short*)(ws + 3 * TOKF);               // ln2-out / attn-out, bf16
  short* BIG  = (short*)(ws + 3 * TOKF + TOKH);        // qkv / hidden / im2col, bf16
  short* WB   = (short*)(ws + 3 * TOKF + TOKH + (size_t)NTOK * 3072 * 2);
  // per-prefix transposed bf16 weights
  const size_t QE = (size_t)3 * 2304 * 768;   // qkv elems per prefix
  const size_t PE = (size_t)3 * 768 * 768;
  const size_t F1E = (size_t)3 * 3072 * 768;
  const size_t F2E = (size_t)3 * 768 * 3072;
  const size_t PFX = QE + PE + F1E + F2E;
  short* WQ[2], *WP[2], *WF1[2], *WF2[2];
  for (int p = 0; p < 2; p++) {
    WQ[p]  = WB + p * PFX;
    WP[p]  = WQ[p] + QE;
    WF1[p] = WP[p] + PE;
    WF2[p] = WF1[p] + F1E;
  }
  short* CW = WB + 2 * PFX;                            // conv weight bf16 (768x608)

  // ---- weight prep (bf16, transposed to [N][K]) ----
  for (int p = 0; p < 2; p++) {
    wt_k<<<dim3(72, 24, 3), 256, 0, stream>>>(W[p][4],  WQ[p],  768, 2304);
    wt_k<<<dim3(24, 24, 3), 256, 0, stream>>>(W[p][6],  WP[p],  768, 768);
    wt_k<<<dim3(96, 24, 3), 256, 0, stream>>>(W[p][10], WF1[p], 768, 3072);
    wt_k<<<dim3(24, 96, 3), 256, 0, stream>>>(W[p][12], WF2[p], 3072, 768);
  }
  convw_k<<<1824, 256, 0, stream>>>(conv_w, CW);

  // ---- patch embedding ----
  im2col_k<<<10944, 256, 0, stream>>>(x, BIG);
  mgemm_k<false, false, false, false><<<dim3(36, 6), 256, 0, stream>>>(
      BIG, CW, conv_b, nullptr, nullptr, Y, 4608, 768, KC);
  assemble_k<<<14208, 256, 0, stream>>>(Y, cls, pos, X);

  for (int phase = 0; phase < 2; phase++) {
    const int Bn = (phase == 0) ? 128 : 4;
    const int Nn = (phase == 0) ? 37 : 1184;
    if (phase == 1) tpos_k<<<14208, 256, 0, stream>>>(X, tpos);
    for (int i = 0; i < 3; i++) {
      const float* pre_g = W[phase][0] + i * DM;
      const float* pre_b = W[phase][1] + i * DM;
      const float* n1_g  = W[phase][2] + i * DM;
      const float* n1_b  = W[phase][3] + i * DM;
      const float* qkv_b = W[phase][5] + i * 2304;
      const float* prj_b = W[phase][7] + i * DM;
      const float* n2_g  = W[phase][8] + i * DM;
      const float* n2_b  = W[phase][9] + i * DM;
      const float* fc1_b = W[phase][11] + i * 3072;
      const float* fc2_b = W[phase][13] + i * DM;
      const short* qkv_w = WQ[phase]  + (size_t)i * 2304 * 768;
      const short* prj_w = WP[phase]  + (size_t)i * 768 * 768;
      const short* fc1_w = WF1[phase] + (size_t)i * 3072 * 768;
      const short* fc2_w = WF2[phase] + (size_t)i * 768 * 3072;

      ln2_k<<<NTOK, 256, 0, stream>>>(X, pre_g, pre_b, n1_g, n1_b, XN, TA2);
      mgemm_k<false, true, false, false><<<dim3(37, 18), 256, 0, stream>>>(
          TA2, qkv_w, qkv_b, nullptr, nullptr, BIG, NTOK, 2304, DM);
      attn_k<<<dim3(Bn * NHEAD, (Nn + 63) / 64), 256, 0, stream>>>(BIG, TA2, Bn, Nn);
      mgemm_k<false, false, true, false><<<dim3(37, 6), 256, 0, stream>>>(
          TA2, prj_w, prj_b, XN, nullptr, Y, NTOK, DM, DM);
      ln_k<true><<<NTOK, 256, 0, stream>>>(Y, n2_g, n2_b, TA2);
      mgemm_k<true, true, false, false><<<dim3(37, 24), 256, 0, stream>>>(
          TA2, fc1_w, fc1_b, nullptr, nullptr, BIG, NTOK, 3072, DM);
      mgemm_k<false, false, true, true><<<dim3(37, 6), 256, 0, stream>>>(
          BIG, fc2_w, fc2_b, Y, X, X, NTOK, DM, 3072);
    }
  }
  mean_k<<<dim3(4, 3), 256, 0, stream>>>(X, (float*)d_out);
}

// Round 4
// 2540.379 us; speedup vs baseline: 3.5337x; 1.0496x over previous
//
#include <hip/hip_runtime.h>
#include <math.h>

// ---------------- constants ----------------
// B=4, T=32, IMG=84, P=14, D=768, H=12, L=3, GP=6, NP=36, N=37, FF=3072, HD=64
#define NTOK 4736
#define DM   768
#define NHEAD 12
#define KC   608          // conv K padded (588 -> 608, multiple of 32)

typedef __attribute__((ext_vector_type(8))) short bf16x8;
typedef __attribute__((ext_vector_type(4))) float f32x4;

__device__ inline short f2bf(float f) {
  union { float f; unsigned u; } v; v.f = f;
  unsigned r = v.u + 0x7FFF + ((v.u >> 16) & 1);   // RNE
  return (short)(r >> 16);
}

__device__ inline void gload16(const void* g, void* l) {
  __builtin_amdgcn_global_load_lds(
      (const __attribute__((address_space(1))) void*)g,
      (__attribute__((address_space(3))) void*)l, 16, 0, 0);
}

// ---------------- im2col: (128,3,84,84) fp32 -> (4608, 608) bf16, zero-pad ----
__global__ __launch_bounds__(256) void im2col_k(const float* __restrict__ x,
                                                short* __restrict__ col) {
  int i = blockIdx.x * 256 + threadIdx.x;       // < 4608*608
  int r = i / KC, k = i % KC;
  short v = 0;
  if (k < 588) {
    int bt = r / 36, p = r % 36;
    int gy = p / 6, gx = p % 6;
    int c = k / 196, rem = k % 196;
    int ky = rem / 14, kx = rem % 14;
    v = f2bf(x[(((size_t)bt * 3 + c) * 84 + gy * 14 + ky) * 84 + gx * 14 + kx]);
  }
  col[i] = v;
}

// ---------------- conv weight: (768,588) fp32 -> (768,608) bf16 zero-pad ------
__global__ __launch_bounds__(256) void convw_k(const float* __restrict__ w,
                                               short* __restrict__ out) {
  int i = blockIdx.x * 256 + threadIdx.x;       // < 768*608
  int n = i / KC, k = i % KC;
  out[i] = (k < 588) ? f2bf(w[(size_t)n * 588 + k]) : (short)0;
}

// ---------------- weight transpose+convert: (L,K,N) fp32 -> (L,N,K) bf16 ------
__global__ __launch_bounds__(256) void wt_k(const float* __restrict__ in,
                                            short* __restrict__ out,
                                            int K, int N) {
  __shared__ float tile[32][33];
  const int l = blockIdx.z;
  in  += (size_t)l * K * N;
  out += (size_t)l * N * K;
  const int n0 = blockIdx.x * 32, k0 = blockIdx.y * 32;
  const int tx = threadIdx.x & 31, ty = threadIdx.x >> 5;   // ty 0..7
#pragma unroll
  for (int r = 0; r < 4; r++)
    tile[ty + 8 * r][tx] = in[(size_t)(k0 + ty + 8 * r) * N + n0 + tx];
  __syncthreads();
#pragma unroll
  for (int r = 0; r < 4; r++)
    out[(size_t)(n0 + ty + 8 * r) * K + k0 + tx] = f2bf(tile[tx][ty + 8 * r]);
}

// ---------------- token assembly: cls + patches + pos (fp32) ----------------
__global__ __launch_bounds__(256) void assemble_k(const float* __restrict__ conv_out,
                                                  const float* __restrict__ cls,
                                                  const float* __restrict__ pos,
                                                  float* __restrict__ X) {
  int i = blockIdx.x * 256 + threadIdx.x;       // < 4736*768
  int t = i / DM, d = i % DM;
  int bt = t / 37, n = t % 37;
  float v = (n == 0) ? cls[d] : conv_out[((size_t)bt * 36 + (n - 1)) * DM + d];
  X[i] = v + pos[n * DM + d];
}

// ---------------- temporal pos add ----------------
__global__ __launch_bounds__(256) void tpos_k(float* __restrict__ X,
                                              const float* __restrict__ tpos) {
  int i = blockIdx.x * 256 + threadIdx.x;
  int row = i / DM, d = i % DM;
  int tt = (row % 1184) / 37;
  X[i] += tpos[tt * DM + d];
}

// ---------------- LayerNorm over 768; template output dtype ----------------
template <bool OBF>
__global__ __launch_bounds__(256) void ln_k(const float* __restrict__ in,
                                            const float* __restrict__ g,
                                            const float* __restrict__ b,
                                            void* __restrict__ outp) {
  int r = blockIdx.x;
  int tid = threadIdx.x;
  const float* xr = in + (size_t)r * DM;
  float v0 = xr[tid], v1 = xr[tid + 256], v2 = xr[tid + 512];
  float s  = v0 + v1 + v2;
  float sq = v0 * v0 + v1 * v1 + v2 * v2;
#pragma unroll
  for (int off = 32; off; off >>= 1) {
    s  += __shfl_down(s, off);
    sq += __shfl_down(sq, off);
  }
  __shared__ float ss[4], sg[4];
  if ((tid & 63) == 0) { ss[tid >> 6] = s; sg[tid >> 6] = sq; }
  __syncthreads();
  float S = ss[0] + ss[1] + ss[2] + ss[3];
  float Q = sg[0] + sg[1] + sg[2] + sg[3];
  float mean = S * (1.f / 768.f);
  float var  = Q * (1.f / 768.f) - mean * mean;
  float rs = rsqrtf(var + 1e-5f);
  float o0 = (v0 - mean) * rs * g[tid]       + b[tid];
  float o1 = (v1 - mean) * rs * g[tid + 256] + b[tid + 256];
  float o2 = (v2 - mean) * rs * g[tid + 512] + b[tid + 512];
  if (OBF) {
    short* o = (short*)outp + (size_t)r * DM;
    o[tid] = f2bf(o0); o[tid + 256] = f2bf(o1); o[tid + 512] = f2bf(o2);
  } else {
    float* o = (float*)outp + (size_t)r * DM;
    o[tid] = o0; o[tid + 256] = o1; o[tid + 512] = o2;
  }
}

// ---------------- fused double LayerNorm: xn = LN(x,pre) [fp32], w = LN(xn,n1) [bf16]
__global__ __launch_bounds__(256) void ln2_k(const float* __restrict__ in,
                                             const float* __restrict__ g1,
                                             const float* __restrict__ b1,
                                             const float* __restrict__ g2,
                                             const float* __restrict__ b2,
                                             float* __restrict__ xn,
                                             short* __restrict__ w) {
  int r = blockIdx.x;
  int tid = threadIdx.x;
  const float* xr = in + (size_t)r * DM;
  float v0 = xr[tid], v1 = xr[tid + 256], v2 = xr[tid + 512];
  float s  = v0 + v1 + v2;
  float sq = v0 * v0 + v1 * v1 + v2 * v2;
#pragma unroll
  for (int off = 32; off; off >>= 1) {
    s  += __shfl_down(s, off);
    sq += __shfl_down(sq, off);
  }
  __shared__ float ss[4], sg[4], ss2[4], sg2[4];
  if ((tid & 63) == 0) { ss[tid >> 6] = s; sg[tid >> 6] = sq; }
  __syncthreads();
  float S = ss[0] + ss[1] + ss[2] + ss[3];
  float Q = sg[0] + sg[1] + sg[2] + sg[3];
  float mean = S * (1.f / 768.f);
  float var  = Q * (1.f / 768.f) - mean * mean;
  float rs = rsqrtf(var + 1e-5f);
  float x0 = (v0 - mean) * rs * g1[tid]       + b1[tid];
  float x1 = (v1 - mean) * rs * g1[tid + 256] + b1[tid + 256];
  float x2 = (v2 - mean) * rs * g1[tid + 512] + b1[tid + 512];
  float* xo = xn + (size_t)r * DM;
  xo[tid] = x0; xo[tid + 256] = x1; xo[tid + 512] = x2;
  float s2  = x0 + x1 + x2;
  float sq2 = x0 * x0 + x1 * x1 + x2 * x2;
#pragma unroll
  for (int off = 32; off; off >>= 1) {
    s2  += __shfl_down(s2, off);
    sq2 += __shfl_down(sq2, off);
  }
  if ((tid & 63) == 0) { ss2[tid >> 6] = s2; sg2[tid >> 6] = sq2; }
  __syncthreads();
  float S2 = ss2[0] + ss2[1] + ss2[2] + ss2[3];
  float Q2 = sg2[0] + sg2[1] + sg2[2] + sg2[3];
  float mean2 = S2 * (1.f / 768.f);
  float var2  = Q2 * (1.f / 768.f) - mean2 * mean2;
  float rs2 = rsqrtf(var2 + 1e-5f);
  short* wo = w + (size_t)r * DM;
  wo[tid]       = f2bf((x0 - mean2) * rs2 * g2[tid]       + b2[tid]);
  wo[tid + 256] = f2bf((x1 - mean2) * rs2 * g2[tid + 256] + b2[tid + 256]);
  wo[tid + 512] = f2bf((x2 - mean2) * rs2 * g2[tid + 512] + b2[tid + 512]);
}

// ---------------- MFMA bf16 GEMM, 2-phase double-buffered pipeline ----------
// C = A(MxK) * B^T(NxK) [+bias][gelu][+r1][+r2]. 128x128 tile, 4 waves (2x2),
// BK=32, LDS 2x16KB double-buffer. STAGE(t+1) issued before compute of t;
// single __syncthreads (vmcnt0+barrier) per K-step (T3-minimum recipe).
// Bijective XCD swizzle (m204), by-fast: consecutive blocks share A panel.
template <bool GELU, bool OBF, bool HASR1, bool HASR2>
__global__ __launch_bounds__(256) void mgemm_k(const short* __restrict__ A,
                                               const short* __restrict__ Bw,
                                               const float* __restrict__ bias,
                                               const float* __restrict__ r1,
                                               const float* __restrict__ r2,
                                               void* __restrict__ Cout,
                                               int M, int N, int K) {
  __shared__ short As[2][4][128][8];
  __shared__ short Bs[2][4][128][8];

  // XCD-aware bijective swizzle over linear block id
  const int nwg  = gridDim.x * gridDim.y;
  const int orig = blockIdx.x + gridDim.x * blockIdx.y;
  const int qq = nwg >> 3, rr = nwg & 7;
  const int xcd = orig & 7, sub = orig >> 3;
  const int wgid = ((xcd < rr) ? xcd * (qq + 1) : rr * (qq + 1) + (xcd - rr) * qq) + sub;
  const int gy = gridDim.y;
  const int bm = (wgid / gy) * 128, bn = (wgid % gy) * 128;

  const int tid = threadIdx.x, wid = tid >> 6, lane = tid & 63;
  const int lr = lane & 15, lg = lane >> 4;
  const int wm = (wid >> 1) * 64, wn = (wid & 1) * 64;

  f32x4 acc[4][4];
#pragma unroll
  for (int m = 0; m < 4; m++)
#pragma unroll
    for (int n = 0; n < 4; n++) acc[m][n] = (f32x4){0.f, 0.f, 0.f, 0.f};

  const short* Ab = A  + (size_t)bm * K + wid * 8;
  const short* Bb = Bw + (size_t)bn * K + wid * 8;

#define STAGE(buf, kk)                                                   \
  do {                                                                   \
    gload16(Ab + (size_t)lane * K + (kk),        &As[buf][wid][0][0]);   \
    gload16(Ab + (size_t)(lane + 64) * K + (kk), &As[buf][wid][64][0]);  \
    gload16(Bb + (size_t)lane * K + (kk),        &Bs[buf][wid][0][0]);   \
    gload16(Bb + (size_t)(lane + 64) * K + (kk), &Bs[buf][wid][64][0]);  \
  } while (0)

  STAGE(0, 0);
  __syncthreads();

  int cur = 0;
  for (int k0 = 0; k0 < K; k0 += 32) {
    if (k0 + 32 < K) STAGE(cur ^ 1, k0 + 32);   // prefetch next tile (in flight
                                                // during this tile's compute)
    bf16x8 af[4], bfr[4];
#pragma unroll
    for (int m = 0; m < 4; m++)
      af[m] = *reinterpret_cast<const bf16x8*>(&As[cur][lg][wm + m * 16 + lr][0]);
#pragma unroll
    for (int n = 0; n < 4; n++)
      bfr[n] = *reinterpret_cast<const bf16x8*>(&Bs[cur][lg][wn + n * 16 + lr][0]);
#pragma unroll
    for (int m = 0; m < 4; m++)
#pragma unroll
      for (int n = 0; n < 4; n++)
        acc[m][n] = __builtin_amdgcn_mfma_f32_16x16x32_bf16(af[m], bfr[n], acc[m][n], 0, 0, 0);
    __syncthreads();   // vmcnt(0)+lgkmcnt(0)+barrier: next buf ready, cur reusable
    cur ^= 1;
  }
#undef STAGE

  // epilogue: row = bm+wm+m*16+lg*4+r, col = bn+wn+n*16+lr
#pragma unroll
  for (int m = 0; m < 4; m++) {
#pragma unroll
    for (int r = 0; r < 4; r++) {
      int row = bm + wm + m * 16 + lg * 4 + r;
#pragma unroll
      for (int n = 0; n < 4; n++) {
        int col = bn + wn + n * 16 + lr;
        size_t idx = (size_t)row * N + col;
        float v = acc[m][n][r];
        if (bias) v += bias[col];
        if (GELU) v = 0.5f * v * (1.f + erff(v * 0.70710678118654752f));
        if (HASR1) v += r1[idx];
        if (HASR2) v += r2[idx];
        if (OBF) ((short*)Cout)[idx] = f2bf(v);
        else     ((float*)Cout)[idx] = v;
      }
    }
  }
}

// ---------------- MFMA bf16 flash attention (bf16 qkv in, bf16 out) ----------
__global__ __launch_bounds__(256) void attn_k(const short* __restrict__ qkv,
                                              short* __restrict__ out,
                                              int Bn, int Nn) {
  const int b = blockIdx.x / NHEAD, h = blockIdx.x % NHEAD;
  const int q0 = blockIdx.y * 64;
  const int tid = threadIdx.x;
  const int wid = tid >> 6, lane = tid & 63;
  const int lr = lane & 15, lg = lane >> 4;

  __shared__ short Ks[32][40];
  __shared__ short Vt[64][40];
  __shared__ short Ps[4][16][40];

  const int qrow_in = q0 + wid * 16 + lr;
  const int qcl = (qrow_in < Nn) ? qrow_in : (Nn - 1);
  const short* qp = qkv + ((size_t)(b * Nn + qcl)) * 2304 + h * 64 + lg * 8;
  bf16x8 qa0 = *reinterpret_cast<const bf16x8*>(qp);
  bf16x8 qa1 = *reinterpret_cast<const bf16x8*>(qp + 32);

  f32x4 oo[4];
#pragma unroll
  for (int dg = 0; dg < 4; dg++) oo[dg] = (f32x4){0.f, 0.f, 0.f, 0.f};
  float mm[4] = {-1e30f, -1e30f, -1e30f, -1e30f};
  float ll[4] = {0.f, 0.f, 0.f, 0.f};

  const int skey = tid >> 3;
  const int sd   = (tid & 7) * 8;

  for (int k0 = 0; k0 < Nn; k0 += 32) {
    {
      int kg = k0 + skey; if (kg >= Nn) kg = Nn - 1;
      const short* kp = qkv + ((size_t)(b * Nn + kg)) * 2304 + 768 + h * 64 + sd;
      bf16x8 kv = *reinterpret_cast<const bf16x8*>(kp);
      bf16x8 vv = *reinterpret_cast<const bf16x8*>(kp + 768);
      *reinterpret_cast<bf16x8*>(&Ks[skey][sd]) = kv;
#pragma unroll
      for (int i = 0; i < 8; i++) Vt[sd + i][skey] = vv[i];
    }
    __syncthreads();

    f32x4 c0 = (f32x4){0.f, 0.f, 0.f, 0.f};
    f32x4 c1 = (f32x4){0.f, 0.f, 0.f, 0.f};
    {
      bf16x8 kb;
      kb = *reinterpret_cast<const bf16x8*>(&Ks[lr][lg * 8]);
      c0 = __builtin_amdgcn_mfma_f32_16x16x32_bf16(qa0, kb, c0, 0, 0, 0);
      kb = *reinterpret_cast<const bf16x8*>(&Ks[lr][32 + lg * 8]);
      c0 = __builtin_amdgcn_mfma_f32_16x16x32_bf16(qa1, kb, c0, 0, 0, 0);
      kb = *reinterpret_cast<const bf16x8*>(&Ks[16 + lr][lg * 8]);
      c1 = __builtin_amdgcn_mfma_f32_16x16x32_bf16(qa0, kb, c1, 0, 0, 0);
      kb = *reinterpret_cast<const bf16x8*>(&Ks[16 + lr][32 + lg * 8]);
      c1 = __builtin_amdgcn_mfma_f32_16x16x32_bf16(qa1, kb, c1, 0, 0, 0);
    }
#pragma unroll
    for (int r = 0; r < 4; r++) { c0[r] *= 0.125f; c1[r] *= 0.125f; }

    if (k0 + 32 > Nn) {
      if (k0 + lr >= Nn)      { c0[0] = c0[1] = c0[2] = c0[3] = -1e30f; }
      if (k0 + 16 + lr >= Nn) { c1[0] = c1[1] = c1[2] = c1[3] = -1e30f; }
    }

#pragma unroll
    for (int r = 0; r < 4; r++) {
      float t = fmaxf(c0[r], c1[r]);
      t = fmaxf(t, __shfl_xor(t, 1, 16));
      t = fmaxf(t, __shfl_xor(t, 2, 16));
      t = fmaxf(t, __shfl_xor(t, 4, 16));
      t = fmaxf(t, __shfl_xor(t, 8, 16));
      float mn = fmaxf(mm[r], t);
      float sc = __expf(mm[r] - mn);
      float p0 = __expf(c0[r] - mn);
      float p1 = __expf(c1[r] - mn);
      float ps = p0 + p1;
      ps += __shfl_xor(ps, 1, 16);
      ps += __shfl_xor(ps, 2, 16);
      ps += __shfl_xor(ps, 4, 16);
      ps += __shfl_xor(ps, 8, 16);
      ll[r] = ll[r] * sc + ps;
      mm[r] = mn;
      oo[0][r] *= sc; oo[1][r] *= sc; oo[2][r] *= sc; oo[3][r] *= sc;
      Ps[wid][lg * 4 + r][lr]      = f2bf(p0);
      Ps[wid][lg * 4 + r][16 + lr] = f2bf(p1);
    }

    {
      bf16x8 pa = *reinterpret_cast<const bf16x8*>(&Ps[wid][lr][lg * 8]);
#pragma unroll
      for (int dg = 0; dg < 4; dg++) {
        bf16x8 vb = *reinterpret_cast<const bf16x8*>(&Vt[dg * 16 + lr][lg * 8]);
        oo[dg] = __builtin_amdgcn_mfma_f32_16x16x32_bf16(pa, vb, oo[dg], 0, 0, 0);
      }
    }
    __syncthreads();
  }

#pragma unroll
  for (int r = 0; r < 4; r++) {
    int qr = q0 + wid * 16 + lg * 4 + r;
    if (qr < Nn) {
      float inv = 1.f / ll[r];
      short* op = out + ((size_t)(b * Nn + qr)) * DM + h * 64 + lr;
      op[0]  = f2bf(oo[0][r] * inv);
      op[16] = f2bf(oo[1][r] * inv);
      op[32] = f2bf(oo[2][r] * inv);
      op[48] = f2bf(oo[3][r] * inv);
    }
  }
}

// ---------------- mean over sequence: (4,1184,768) -> (4,768) ----------------
__global__ __launch_bounds__(256) void mean_k(const float* __restrict__ X,
                                              float* __restrict__ out) {
  int b = blockIdx.x;
  int d = blockIdx.y * 256 + threadIdx.x;
  float s = 0.f;
  for (int r = 0; r < 1184; r++) s += X[((size_t)b * 1184 + r) * DM + d];
  out[b * DM + d] = s * (1.f / 1184.f);
}

// ---------------- orchestration ----------------
extern "C" void kernel_launch(void* const* d_in, const int* in_sizes, int n_in,
                              void* d_out, int out_size, void* d_ws, size_t ws_size,
                              hipStream_t stream) {
  (void)in_sizes; (void)n_in; (void)out_size; (void)ws_size;
  const float* x      = (const float*)d_in[0];
  const float* conv_w = (const float*)d_in[1];
  const float* conv_b = (const float*)d_in[2];
  const float* cls    = (const float*)d_in[3];
  const float* pos    = (const float*)d_in[4];
  const float* tpos   = (const float*)d_in[5];
  const float* W[2][14];
  for (int p = 0; p < 2; p++)
    for (int i = 0; i < 14; i++)
      W[p][i] = (const float*)d_in[6 + p * 14 + i];

  char* ws = (char*)d_ws;
  const size_t TOKF = (size_t)NTOK * DM * 4;
  const size_t TOKH = (size_t)NTOK * DM * 2;
  float* X    = (float*)(ws);
  float* XN   = (float*)(ws + TOKF);
  float* Y    = (float*)(ws + 2 * TOKF);
  short* TA2  = (short*)(ws + 3 * TOKF);
  short* BIG  = (short*)(ws + 3 * TOKF + TOKH);
  short* WB   = (short*)(ws + 3 * TOKF + TOKH + (size_t)NTOK * 3072 * 2);
  const size_t QE = (size_t)3 * 2304 * 768;
  const size_t PE = (size_t)3 * 768 * 768;
  const size_t F1E = (size_t)3 * 3072 * 768;
  const size_t F2E = (size_t)3 * 768 * 3072;
  const size_t PFX = QE + PE + F1E + F2E;
  short* WQ[2], *WP[2], *WF1[2], *WF2[2];
  for (int p = 0; p < 2; p++) {
    WQ[p]  = WB + p * PFX;
    WP[p]  = WQ[p] + QE;
    WF1[p] = WP[p] + PE;
    WF2[p] = WF1[p] + F1E;
  }
  short* CW = WB + 2 * PFX;

  // ---- weight prep (bf16, transposed to [N][K]) ----
  for (int p = 0; p < 2; p++) {
    wt_k<<<dim3(72, 24, 3), 256, 0, stream>>>(W[p][4],  WQ[p],  768, 2304);
    wt_k<<<dim3(24, 24, 3), 256, 0, stream>>>(W[p][6],  WP[p],  768, 768);
    wt_k<<<dim3(96, 24, 3), 256, 0, stream>>>(W[p][10], WF1[p], 768, 3072);
    wt_k<<<dim3(24, 96, 3), 256, 0, stream>>>(W[p][12], WF2[p], 3072, 768);
  }
  convw_k<<<1824, 256, 0, stream>>>(conv_w, CW);

  // ---- patch embedding ----
  im2col_k<<<10944, 256, 0, stream>>>(x, BIG);
  mgemm_k<false, false, false, false><<<dim3(36, 6), 256, 0, stream>>>(
      BIG, CW, conv_b, nullptr, nullptr, Y, 4608, 768, KC);
  assemble_k<<<14208, 256, 0, stream>>>(Y, cls, pos, X);

  for (int phase = 0; phase < 2; phase++) {
    const int Bn = (phase == 0) ? 128 : 4;
    const int Nn = (phase == 0) ? 37 : 1184;
    if (phase == 1) tpos_k<<<14208, 256, 0, stream>>>(X, tpos);
    for (int i = 0; i < 3; i++) {
      const float* pre_g = W[phase][0] + i * DM;
      const float* pre_b = W[phase][1] + i * DM;
      const float* n1_g  = W[phase][2] + i * DM;
      const float* n1_b  = W[phase][3] + i * DM;
      const float* qkv_b = W[phase][5] + i * 2304;
      const float* prj_b = W[phase][7] + i * DM;
      const float* n2_g  = W[phase][8] + i * DM;
      const float* n2_b  = W[phase][9] + i * DM;
      const float* fc1_b = W[phase][11] + i * 3072;
      const float* fc2_b = W[phase][13] + i * DM;
      const short* qkv_w = WQ[phase]  + (size_t)i * 2304 * 768;
      const short* prj_w = WP[phase]  + (size_t)i * 768 * 768;
      const short* fc1_w = WF1[phase] + (size_t)i * 3072 * 768;
      const short* fc2_w = WF2[phase] + (size_t)i * 768 * 3072;

      ln2_k<<<NTOK, 256, 0, stream>>>(X, pre_g, pre_b, n1_g, n1_b, XN, TA2);
      mgemm_k<false, true, false, false><<<dim3(37, 18), 256, 0, stream>>>(
          TA2, qkv_w, qkv_b, nullptr, nullptr, BIG, NTOK, 2304, DM);
      attn_k<<<dim3(Bn * NHEAD, (Nn + 63) / 64), 256, 0, stream>>>(BIG, TA2, Bn, Nn);
      mgemm_k<false, false, true, false><<<dim3(37, 6), 256, 0, stream>>>(
          TA2, prj_w, prj_b, XN, nullptr, Y, NTOK, DM, DM);
      ln_k<true><<<NTOK, 256, 0, stream>>>(Y, n2_g, n2_b, TA2);
      mgemm_k<true, true, false, false><<<dim3(37, 24), 256, 0, stream>>>(
          TA2, fc1_w, fc1_b, nullptr, nullptr, BIG, NTOK, 3072, DM);
      mgemm_k<false, false, true, true><<<dim3(37, 6), 256, 0, stream>>>(
          BIG, fc2_w, fc2_b, Y, X, X, NTOK, DM, 3072);
    }
  }
  mean_k<<<dim3(4, 3), 256, 0, stream>>>(X, (float*)d_out);
}

// Round 5
// 2101.146 us; speedup vs baseline: 4.2724x; 1.2090x over previous
//
#include <hip/hip_runtime.h>
#include <math.h>

// ---------------- constants ----------------
// B=4, T=32, IMG=84, P=14, D=768, H=12, L=3, GP=6, NP=36, N=37, FF=3072, HD=64
#define NTOK 4736
#define DM   768
#define NHEAD 12
#define KC   608          // conv K padded (588 -> 608, multiple of 32)

typedef __attribute__((ext_vector_type(8))) short bf16x8;
typedef __attribute__((ext_vector_type(4))) float f32x4;

__device__ inline short f2bf(float f) {
  union { float f; unsigned u; } v; v.f = f;
  unsigned r = v.u + 0x7FFF + ((v.u >> 16) & 1);   // RNE
  return (short)(r >> 16);
}

__device__ inline void gload16(const void* g, void* l) {
  __builtin_amdgcn_global_load_lds(
      (const __attribute__((address_space(1))) void*)g,
      (__attribute__((address_space(3))) void*)l, 16, 0, 0);
}

// ---------------- im2col: (128,3,84,84) fp32 -> (4608, 608) bf16, zero-pad ----
__global__ __launch_bounds__(256) void im2col_k(const float* __restrict__ x,
                                                short* __restrict__ col) {
  int i = blockIdx.x * 256 + threadIdx.x;       // < 4608*608
  int r = i / KC, k = i % KC;
  short v = 0;
  if (k < 588) {
    int bt = r / 36, p = r % 36;
    int gy = p / 6, gx = p % 6;
    int c = k / 196, rem = k % 196;
    int ky = rem / 14, kx = rem % 14;
    v = f2bf(x[(((size_t)bt * 3 + c) * 84 + gy * 14 + ky) * 84 + gx * 14 + kx]);
  }
  col[i] = v;
}

// ---------------- conv weight: (768,588) fp32 -> (768,608) bf16 zero-pad ------
__global__ __launch_bounds__(256) void convw_k(const float* __restrict__ w,
                                               short* __restrict__ out) {
  int i = blockIdx.x * 256 + threadIdx.x;       // < 768*608
  int n = i / KC, k = i % KC;
  out[i] = (k < 588) ? f2bf(w[(size_t)n * 588 + k]) : (short)0;
}

// ---------------- weight transpose+convert: (L,K,N) fp32 -> (L,N,K) bf16 ------
__global__ __launch_bounds__(256) void wt_k(const float* __restrict__ in,
                                            short* __restrict__ out,
                                            int K, int N) {
  __shared__ float tile[32][33];
  const int l = blockIdx.z;
  in  += (size_t)l * K * N;
  out += (size_t)l * N * K;
  const int n0 = blockIdx.x * 32, k0 = blockIdx.y * 32;
  const int tx = threadIdx.x & 31, ty = threadIdx.x >> 5;   // ty 0..7
#pragma unroll
  for (int r = 0; r < 4; r++)
    tile[ty + 8 * r][tx] = in[(size_t)(k0 + ty + 8 * r) * N + n0 + tx];
  __syncthreads();
#pragma unroll
  for (int r = 0; r < 4; r++)
    out[(size_t)(n0 + ty + 8 * r) * K + k0 + tx] = f2bf(tile[tx][ty + 8 * r]);
}

// ---------------- token assembly: cls + patches + pos (fp32) ----------------
__global__ __launch_bounds__(256) void assemble_k(const float* __restrict__ conv_out,
                                                  const float* __restrict__ cls,
                                                  const float* __restrict__ pos,
                                                  float* __restrict__ X) {
  int i = blockIdx.x * 256 + threadIdx.x;       // < 4736*768
  int t = i / DM, d = i % DM;
  int bt = t / 37, n = t % 37;
  float v = (n == 0) ? cls[d] : conv_out[((size_t)bt * 36 + (n - 1)) * DM + d];
  X[i] = v + pos[n * DM + d];
}

// ---------------- temporal pos add ----------------
__global__ __launch_bounds__(256) void tpos_k(float* __restrict__ X,
                                              const float* __restrict__ tpos) {
  int i = blockIdx.x * 256 + threadIdx.x;
  int row = i / DM, d = i % DM;
  int tt = (row % 1184) / 37;
  X[i] += tpos[tt * DM + d];
}

// ---------------- LayerNorm over 768; template output dtype ----------------
template <bool OBF>
__global__ __launch_bounds__(256) void ln_k(const float* __restrict__ in,
                                            const float* __restrict__ g,
                                            const float* __restrict__ b,
                                            void* __restrict__ outp) {
  int r = blockIdx.x;
  int tid = threadIdx.x;
  const float* xr = in + (size_t)r * DM;
  float v0 = xr[tid], v1 = xr[tid + 256], v2 = xr[tid + 512];
  float s  = v0 + v1 + v2;
  float sq = v0 * v0 + v1 * v1 + v2 * v2;
#pragma unroll
  for (int off = 32; off; off >>= 1) {
    s  += __shfl_down(s, off);
    sq += __shfl_down(sq, off);
  }
  __shared__ float ss[4], sg[4];
  if ((tid & 63) == 0) { ss[tid >> 6] = s; sg[tid >> 6] = sq; }
  __syncthreads();
  float S = ss[0] + ss[1] + ss[2] + ss[3];
  float Q = sg[0] + sg[1] + sg[2] + sg[3];
  float mean = S * (1.f / 768.f);
  float var  = Q * (1.f / 768.f) - mean * mean;
  float rs = rsqrtf(var + 1e-5f);
  float o0 = (v0 - mean) * rs * g[tid]       + b[tid];
  float o1 = (v1 - mean) * rs * g[tid + 256] + b[tid + 256];
  float o2 = (v2 - mean) * rs * g[tid + 512] + b[tid + 512];
  if (OBF) {
    short* o = (short*)outp + (size_t)r * DM;
    o[tid] = f2bf(o0); o[tid + 256] = f2bf(o1); o[tid + 512] = f2bf(o2);
  } else {
    float* o = (float*)outp + (size_t)r * DM;
    o[tid] = o0; o[tid + 256] = o1; o[tid + 512] = o2;
  }
}

// ---------------- fused double LayerNorm: xn = LN(x,pre) [fp32], w = LN(xn,n1) [bf16]
__global__ __launch_bounds__(256) void ln2_k(const float* __restrict__ in,
                                             const float* __restrict__ g1,
                                             const float* __restrict__ b1,
                                             const float* __restrict__ g2,
                                             const float* __restrict__ b2,
                                             float* __restrict__ xn,
                                             short* __restrict__ w) {
  int r = blockIdx.x;
  int tid = threadIdx.x;
  const float* xr = in + (size_t)r * DM;
  float v0 = xr[tid], v1 = xr[tid + 256], v2 = xr[tid + 512];
  float s  = v0 + v1 + v2;
  float sq = v0 * v0 + v1 * v1 + v2 * v2;
#pragma unroll
  for (int off = 32; off; off >>= 1) {
    s  += __shfl_down(s, off);
    sq += __shfl_down(sq, off);
  }
  __shared__ float ss[4], sg[4], ss2[4], sg2[4];
  if ((tid & 63) == 0) { ss[tid >> 6] = s; sg[tid >> 6] = sq; }
  __syncthreads();
  float S = ss[0] + ss[1] + ss[2] + ss[3];
  float Q = sg[0] + sg[1] + sg[2] + sg[3];
  float mean = S * (1.f / 768.f);
  float var  = Q * (1.f / 768.f) - mean * mean;
  float rs = rsqrtf(var + 1e-5f);
  float x0 = (v0 - mean) * rs * g1[tid]       + b1[tid];
  float x1 = (v1 - mean) * rs * g1[tid + 256] + b1[tid + 256];
  float x2 = (v2 - mean) * rs * g1[tid + 512] + b1[tid + 512];
  float* xo = xn + (size_t)r * DM;
  xo[tid] = x0; xo[tid + 256] = x1; xo[tid + 512] = x2;
  float s2  = x0 + x1 + x2;
  float sq2 = x0 * x0 + x1 * x1 + x2 * x2;
#pragma unroll
  for (int off = 32; off; off >>= 1) {
    s2  += __shfl_down(s2, off);
    sq2 += __shfl_down(sq2, off);
  }
  if ((tid & 63) == 0) { ss2[tid >> 6] = s2; sg2[tid >> 6] = sq2; }
  __syncthreads();
  float S2 = ss2[0] + ss2[1] + ss2[2] + ss2[3];
  float Q2 = sg2[0] + sg2[1] + sg2[2] + sg2[3];
  float mean2 = S2 * (1.f / 768.f);
  float var2  = Q2 * (1.f / 768.f) - mean2 * mean2;
  float rs2 = rsqrtf(var2 + 1e-5f);
  short* wo = w + (size_t)r * DM;
  wo[tid]       = f2bf((x0 - mean2) * rs2 * g2[tid]       + b2[tid]);
  wo[tid + 256] = f2bf((x1 - mean2) * rs2 * g2[tid + 256] + b2[tid + 256]);
  wo[tid + 512] = f2bf((x2 - mean2) * rs2 * g2[tid + 512] + b2[tid + 512]);
}

// ---------------- MFMA bf16 GEMM, 2-phase double-buffered pipeline ----------
// C = A(MxK) * B^T(NxK) [+bias][gelu][+r1][+r2]. Tile BM x 128 (BM=128: 4 waves
// 2x2, 64x64 each; BM=64: 4 waves 1x4, 64x32 each). BK=32, LDS double-buffer.
// BM=64 doubles grid size for the small-N GEMMs (proj/fc2/conv) so >=2 blocks/CU.
template <int BM, bool GELU, bool OBF, bool HASR1, bool HASR2>
__global__ __launch_bounds__(256) void mgemm_k(const short* __restrict__ A,
                                               const short* __restrict__ Bw,
                                               const float* __restrict__ bias,
                                               const float* __restrict__ r1,
                                               const float* __restrict__ r2,
                                               void* __restrict__ Cout,
                                               int M, int N, int K) {
  __shared__ short As[2][4][BM][8];
  __shared__ short Bs[2][4][128][8];
  constexpr int NF = (BM == 128) ? 4 : 2;   // n-frags per wave

  // XCD-aware bijective swizzle over linear block id (m204)
  const int nwg  = gridDim.x * gridDim.y;
  const int orig = blockIdx.x + gridDim.x * blockIdx.y;
  const int qq = nwg >> 3, rr = nwg & 7;
  const int xcd = orig & 7, sub = orig >> 3;
  const int wgid = ((xcd < rr) ? xcd * (qq + 1) : rr * (qq + 1) + (xcd - rr) * qq) + sub;
  const int gy = gridDim.y;
  const int bm = (wgid / gy) * BM, bn = (wgid % gy) * 128;

  const int tid = threadIdx.x, wid = tid >> 6, lane = tid & 63;
  const int lr = lane & 15, lg = lane >> 4;
  const int wm = (BM == 128) ? (wid >> 1) * 64 : 0;
  const int wn = (BM == 128) ? (wid & 1) * 64 : wid * 32;

  f32x4 acc[4][NF];
#pragma unroll
  for (int m = 0; m < 4; m++)
#pragma unroll
    for (int n = 0; n < NF; n++) acc[m][n] = (f32x4){0.f, 0.f, 0.f, 0.f};

  const short* Ab = A  + (size_t)bm * K + wid * 8;
  const short* Bb = Bw + (size_t)bn * K + wid * 8;

#define STAGE(buf, kk)                                                     \
  do {                                                                     \
    gload16(Ab + (size_t)lane * K + (kk), &As[buf][wid][0][0]);            \
    if (BM == 128)                                                         \
      gload16(Ab + (size_t)(lane + 64) * K + (kk), &As[buf][wid][BM==128?64:0][0]); \
    gload16(Bb + (size_t)lane * K + (kk),        &Bs[buf][wid][0][0]);     \
    gload16(Bb + (size_t)(lane + 64) * K + (kk), &Bs[buf][wid][64][0]);    \
  } while (0)

  STAGE(0, 0);
  __syncthreads();

  int cur = 0;
  for (int k0 = 0; k0 < K; k0 += 32) {
    if (k0 + 32 < K) STAGE(cur ^ 1, k0 + 32);   // prefetch next tile
    bf16x8 af[4], bfr[NF];
#pragma unroll
    for (int m = 0; m < 4; m++)
      af[m] = *reinterpret_cast<const bf16x8*>(&As[cur][lg][wm + m * 16 + lr][0]);
#pragma unroll
    for (int n = 0; n < NF; n++)
      bfr[n] = *reinterpret_cast<const bf16x8*>(&Bs[cur][lg][wn + n * 16 + lr][0]);
#pragma unroll
    for (int m = 0; m < 4; m++)
#pragma unroll
      for (int n = 0; n < NF; n++)
        acc[m][n] = __builtin_amdgcn_mfma_f32_16x16x32_bf16(af[m], bfr[n], acc[m][n], 0, 0, 0);
    __syncthreads();
    cur ^= 1;
  }
#undef STAGE

  // epilogue: row = bm+wm+m*16+lg*4+r, col = bn+wn+n*16+lr
#pragma unroll
  for (int m = 0; m < 4; m++) {
#pragma unroll
    for (int r = 0; r < 4; r++) {
      int row = bm + wm + m * 16 + lg * 4 + r;
#pragma unroll
      for (int n = 0; n < NF; n++) {
        int col = bn + wn + n * 16 + lr;
        size_t idx = (size_t)row * N + col;
        float v = acc[m][n][r];
        if (bias) v += bias[col];
        if (GELU) v = 0.5f * v * (1.f + erff(v * 0.70710678118654752f));
        if (HASR1) v += r1[idx];
        if (HASR2) v += r2[idx];
        if (OBF) ((short*)Cout)[idx] = f2bf(v);
        else     ((float*)Cout)[idx] = v;
      }
    }
  }
}

// ---------------- MFMA bf16 flash attention v2 ----------
// qkv: (Bn*Nn, 2304) bf16, layout [s(3)][h(12)][d(64)].  out: (Bn*Nn, 768) bf16.
// grid: (Bn*12, ceil(Nn/64)); block 256 = 4 waves, each wave owns 16 q-rows.
// KVBLK=64; K/V/P tiles in [64][64]-short LDS with slot-XOR swizzle
// (col ^ ((row&7)<<3), 16B granules) -> conflict-free b128 reads AND scalar
// transposed V stores. Bijective XCD swizzle clusters same-(b,h) blocks.
__global__ __launch_bounds__(256) void attn_k(const short* __restrict__ qkv,
                                              short* __restrict__ out,
                                              int Bn, int Nn) {
  const int gx = gridDim.x, gy = gridDim.y;
  const int nwg = gx * gy;
  const int orig = blockIdx.x + gx * blockIdx.y;
  const int qq = nwg >> 3, rr = nwg & 7;
  const int xcd = orig & 7, sub = orig >> 3;
  const int wgid = ((xcd < rr) ? xcd * (qq + 1) : rr * (qq + 1) + (xcd - rr) * qq) + sub;
  const int bh = wgid / gy;          // consecutive wgid -> same (b,h): K/V L2 reuse
  const int qb = wgid % gy;
  const int b = bh / NHEAD, h = bh % NHEAD;
  const int q0 = qb * 64;

  const int tid = threadIdx.x;
  const int wid = tid >> 6, lane = tid & 63;
  const int lr = lane & 15, lg = lane >> 4;

  __shared__ short Ks[64][64];       // [key][d], slot-XOR swizzled
  __shared__ short Vt[64][64];       // [d][key], slot-XOR swizzled
  __shared__ short Ps[4][16][64];    // per-wave [qrow][key], slot-XOR swizzled

  // ---- Q fragments (A-operand rows = lr) ----
  const int qrow_in = q0 + wid * 16 + lr;
  const int qcl = (qrow_in < Nn) ? qrow_in : (Nn - 1);
  const short* qp = qkv + ((size_t)(b * Nn + qcl)) * 2304 + h * 64 + lg * 8;
  bf16x8 qa0 = *reinterpret_cast<const bf16x8*>(qp);
  bf16x8 qa1 = *reinterpret_cast<const bf16x8*>(qp + 32);

  f32x4 oo[4];
#pragma unroll
  for (int dg = 0; dg < 4; dg++) oo[dg] = (f32x4){0.f, 0.f, 0.f, 0.f};
  float mm[4] = {-1e30f, -1e30f, -1e30f, -1e30f};
  float ll[4] = {0.f, 0.f, 0.f, 0.f};

  // staging assignments
  const int skey = tid >> 2;            // K: 0..63 key
  const int sdq  = (tid & 3) * 16;      // K: d-offset 0/16/32/48
  const int vkey = tid & 63;            // V: key = lane
  const int vd0  = wid * 16;            // V: d-range per wave

  const int swr = (lr & 7) << 3;        // read-side XOR (row&7 = lr&7)

  for (int k0 = 0; k0 < Nn; k0 += 64) {
    {  // ---- stage K rows [key][dq..dq+15], two swizzled b128 writes ----
      int kg = k0 + skey; if (kg >= Nn) kg = Nn - 1;
      const short* kp = qkv + ((size_t)(b * Nn + kg)) * 2304 + 768 + h * 64 + sdq;
      bf16x8 ka = *reinterpret_cast<const bf16x8*>(kp);
      bf16x8 kb = *reinterpret_cast<const bf16x8*>(kp + 8);
      const int ksw = (skey & 7) << 3;
      *reinterpret_cast<bf16x8*>(&Ks[skey][sdq ^ ksw])       = ka;
      *reinterpret_cast<bf16x8*>(&Ks[skey][(sdq + 8) ^ ksw]) = kb;
      // ---- stage V transposed: thread owns key=vkey, d=vd0..vd0+15 ----
      int vg = k0 + vkey; if (vg >= Nn) vg = Nn - 1;
      const short* vp = qkv + ((size_t)(b * Nn + vg)) * 2304 + 1536 + h * 64 + vd0;
      bf16x8 va = *reinterpret_cast<const bf16x8*>(vp);
      bf16x8 vb = *reinterpret_cast<const bf16x8*>(vp + 8);
#pragma unroll
      for (int i = 0; i < 8; i++) {
        Vt[vd0 + i][vkey ^ (i << 3)]           = va[i];
        Vt[vd0 + 8 + i][vkey ^ (i << 3)]       = vb[i];   // (d&7) == i for both
      }
    }
    __syncthreads();

    // ---- QK^T: S(16x64) via 8 MFMAs (4 key-frags x 2 d-halves) ----
    f32x4 c[4];
#pragma unroll
    for (int kf = 0; kf < 4; kf++) {
      c[kf] = (f32x4){0.f, 0.f, 0.f, 0.f};
      const short* krow = &Ks[kf * 16 + lr][0];
      bf16x8 kb0 = *reinterpret_cast<const bf16x8*>(krow + ((lg * 8) ^ swr));
      c[kf] = __builtin_amdgcn_mfma_f32_16x16x32_bf16(qa0, kb0, c[kf], 0, 0, 0);
      bf16x8 kb1 = *reinterpret_cast<const bf16x8*>(krow + ((32 + lg * 8) ^ swr));
      c[kf] = __builtin_amdgcn_mfma_f32_16x16x32_bf16(qa1, kb1, c[kf], 0, 0, 0);
    }
#pragma unroll
    for (int kf = 0; kf < 4; kf++) {
#pragma unroll
      for (int r = 0; r < 4; r++) c[kf][r] *= 0.125f;
      if (k0 + kf * 16 + lr >= Nn)
        c[kf][0] = c[kf][1] = c[kf][2] = c[kf][3] = -1e30f;
    }

    // ---- online softmax per row r (keys spread over lr lanes x 4 frags) ----
#pragma unroll
    for (int r = 0; r < 4; r++) {
      float t = fmaxf(fmaxf(c[0][r], c[1][r]), fmaxf(c[2][r], c[3][r]));
      t = fmaxf(t, __shfl_xor(t, 1, 16));
      t = fmaxf(t, __shfl_xor(t, 2, 16));
      t = fmaxf(t, __shfl_xor(t, 4, 16));
      t = fmaxf(t, __shfl_xor(t, 8, 16));
      float mn = fmaxf(mm[r], t);
      float sc = __expf(mm[r] - mn);
      float p0 = __expf(c[0][r] - mn);
      float p1 = __expf(c[1][r] - mn);
      float p2 = __expf(c[2][r] - mn);
      float p3 = __expf(c[3][r] - mn);
      float ps = (p0 + p1) + (p2 + p3);
      ps += __shfl_xor(ps, 1, 16);
      ps += __shfl_xor(ps, 2, 16);
      ps += __shfl_xor(ps, 4, 16);
      ps += __shfl_xor(ps, 8, 16);
      ll[r] = ll[r] * sc + ps;
      mm[r] = mn;
      oo[0][r] *= sc; oo[1][r] *= sc; oo[2][r] *= sc; oo[3][r] *= sc;
      const int prow = lg * 4 + r;
      const int psw  = (prow & 7) << 3;
      short* pr = &Ps[wid][prow][0];
      pr[lr ^ psw]        = f2bf(p0);
      pr[(16 + lr) ^ psw] = f2bf(p1);
      pr[(32 + lr) ^ psw] = f2bf(p2);
      pr[(48 + lr) ^ psw] = f2bf(p3);
    }

    // ---- PV: O += P(16x64) * V(64x64) via 8 MFMAs (2 k-steps x 4 d-frags) ----
#pragma unroll
    for (int ks = 0; ks < 2; ks++) {
      bf16x8 pa = *reinterpret_cast<const bf16x8*>(&Ps[wid][lr][(ks * 32 + lg * 8) ^ swr]);
#pragma unroll
      for (int dg = 0; dg < 4; dg++) {
        bf16x8 vb = *reinterpret_cast<const bf16x8*>(
            &Vt[dg * 16 + lr][(ks * 32 + lg * 8) ^ swr]);
        oo[dg] = __builtin_amdgcn_mfma_f32_16x16x32_bf16(pa, vb, oo[dg], 0, 0, 0);
      }
    }
    __syncthreads();
  }

  // ---- store: row = lg*4+r, col = dg*16+lr ----
#pragma unroll
  for (int r = 0; r < 4; r++) {
    int qr = q0 + wid * 16 + lg * 4 + r;
    if (qr < Nn) {
      float inv = 1.f / ll[r];
      short* op = out + ((size_t)(b * Nn + qr)) * DM + h * 64 + lr;
      op[0]  = f2bf(oo[0][r] * inv);
      op[16] = f2bf(oo[1][r] * inv);
      op[32] = f2bf(oo[2][r] * inv);
      op[48] = f2bf(oo[3][r] * inv);
    }
  }
}

// ---------------- mean over sequence: (4,1184,768) -> (4,768) ----------------
__global__ __launch_bounds__(256) void mean_k(const float* __restrict__ X,
                                              float* __restrict__ out) {
  int b = blockIdx.x;
  int d = blockIdx.y * 256 + threadIdx.x;
  float s = 0.f;
  for (int r = 0; r < 1184; r++) s += X[((size_t)b * 1184 + r) * DM + d];
  out[b * DM + d] = s * (1.f / 1184.f);
}

// ---------------- orchestration ----------------
extern "C" void kernel_launch(void* const* d_in, const int* in_sizes, int n_in,
                              void* d_out, int out_size, void* d_ws, size_t ws_size,
                              hipStream_t stream) {
  (void)in_sizes; (void)n_in; (void)out_size; (void)ws_size;
  const float* x      = (const float*)d_in[0];
  const float* conv_w = (const float*)d_in[1];
  const float* conv_b = (const float*)d_in[2];
  const float* cls    = (const float*)d_in[3];
  const float* pos    = (const float*)d_in[4];
  const float* tpos   = (const float*)d_in[5];
  const float* W[2][14];
  for (int p = 0; p < 2; p++)
    for (int i = 0; i < 14; i++)
      W[p][i] = (const float*)d_in[6 + p * 14 + i];

  char* ws = (char*)d_ws;
  const size_t TOKF = (size_t)NTOK * DM * 4;
  const size_t TOKH = (size_t)NTOK * DM * 2;
  float* X    = (float*)(ws);
  float* XN   = (float*)(ws + TOKF);
  float* Y    = (float*)(ws + 2 * TOKF);
  short* TA2  = (short*)(ws + 3 * TOKF);
  short* BIG  = (short*)(ws + 3 * TOKF + TOKH);
  short* WB   = (short*)(ws + 3 * TOKF + TOKH + (size_t)NTOK * 3072 * 2);
  const size_t QE = (size_t)3 * 2304 * 768;
  const size_t PE = (size_t)3 * 768 * 768;
  const size_t F1E = (size_t)3 * 3072 * 768;
  const size_t F2E = (size_t)3 * 768 * 3072;
  const size_t PFX = QE + PE + F1E + F2E;
  short* WQ[2], *WP[2], *WF1[2], *WF2[2];
  for (int p = 0; p < 2; p++) {
    WQ[p]  = WB + p * PFX;
    WP[p]  = WQ[p] + QE;
    WF1[p] = WP[p] + PE;
    WF2[p] = WF1[p] + F1E;
  }
  short* CW = WB + 2 * PFX;

  // ---- weight prep (bf16, transposed to [N][K]) ----
  for (int p = 0; p < 2; p++) {
    wt_k<<<dim3(72, 24, 3), 256, 0, stream>>>(W[p][4],  WQ[p],  768, 2304);
    wt_k<<<dim3(24, 24, 3), 256, 0, stream>>>(W[p][6],  WP[p],  768, 768);
    wt_k<<<dim3(96, 24, 3), 256, 0, stream>>>(W[p][10], WF1[p], 768, 3072);
    wt_k<<<dim3(24, 96, 3), 256, 0, stream>>>(W[p][12], WF2[p], 3072, 768);
  }
  convw_k<<<1824, 256, 0, stream>>>(conv_w, CW);

  // ---- patch embedding ----
  im2col_k<<<10944, 256, 0, stream>>>(x, BIG);
  mgemm_k<64, false, false, false, false><<<dim3(72, 6), 256, 0, stream>>>(
      BIG, CW, conv_b, nullptr, nullptr, Y, 4608, 768, KC);
  assemble_k<<<14208, 256, 0, stream>>>(Y, cls, pos, X);

  for (int phase = 0; phase < 2; phase++) {
    const int Bn = (phase == 0) ? 128 : 4;
    const int Nn = (phase == 0) ? 37 : 1184;
    if (phase == 1) tpos_k<<<14208, 256, 0, stream>>>(X, tpos);
    for (int i = 0; i < 3; i++) {
      const float* pre_g = W[phase][0] + i * DM;
      const float* pre_b = W[phase][1] + i * DM;
      const float* n1_g  = W[phase][2] + i * DM;
      const float* n1_b  = W[phase][3] + i * DM;
      const float* qkv_b = W[phase][5] + i * 2304;
      const float* prj_b = W[phase][7] + i * DM;
      const float* n2_g  = W[phase][8] + i * DM;
      const float* n2_b  = W[phase][9] + i * DM;
      const float* fc1_b = W[phase][11] + i * 3072;
      const float* fc2_b = W[phase][13] + i * DM;
      const short* qkv_w = WQ[phase]  + (size_t)i * 2304 * 768;
      const short* prj_w = WP[phase]  + (size_t)i * 768 * 768;
      const short* fc1_w = WF1[phase] + (size_t)i * 3072 * 768;
      const short* fc2_w = WF2[phase] + (size_t)i * 768 * 3072;

      ln2_k<<<NTOK, 256, 0, stream>>>(X, pre_g, pre_b, n1_g, n1_b, XN, TA2);
      mgemm_k<128, false, true, false, false><<<dim3(37, 18), 256, 0, stream>>>(
          TA2, qkv_w, qkv_b, nullptr, nullptr, BIG, NTOK, 2304, DM);
      attn_k<<<dim3(Bn * NHEAD, (Nn + 63) / 64), 256, 0, stream>>>(BIG, TA2, Bn, Nn);
      mgemm_k<64, false, false, true, false><<<dim3(74, 6), 256, 0, stream>>>(
          TA2, prj_w, prj_b, XN, nullptr, Y, NTOK, DM, DM);
      ln_k<true><<<NTOK, 256, 0, stream>>>(Y, n2_g, n2_b, TA2);
      mgemm_k<128, true, true, false, false><<<dim3(37, 24), 256, 0, stream>>>(
          TA2, fc1_w, fc1_b, nullptr, nullptr, BIG, NTOK, 3072, DM);
      mgemm_k<64, false, false, true, true><<<dim3(74, 6), 256, 0, stream>>>(
          BIG, fc2_w, fc2_b, Y, X, X, NTOK, DM, 3072);
    }
  }
  mean_k<<<dim3(4, 3), 256, 0, stream>>>(X, (float*)d_out);
}